// Round 5
// baseline (213.440 us; speedup 1.0000x reference)
//
#include <hip/hip_runtime.h>
#include <hip/hip_bf16.h>

#define BB 8
#define TT 256
#define DIN 64
#define DD 128

__device__ __forceinline__ float gelu_tanh(float x) {
  float x3 = x * x * x;
  return 0.5f * x * (1.0f + tanhf(0.7978845608028654f * (x + 0.044715f * x3)));
}
__device__ __forceinline__ float sigmoidf(float x) {
  return 1.0f / (1.0f + __expf(-x));
}

template <typename T> __device__ __forceinline__ float getv(const void* p, int i);
template <> __device__ __forceinline__ float getv<float>(const void* p, int i) {
  return ((const float*)p)[i];
}
template <> __device__ __forceinline__ float getv<__hip_bfloat16>(const void* p, int i) {
  return __bfloat162float(((const __hip_bfloat16*)p)[i]);
}

// DPP-based add from a statically-controlled source lane. All-VALU
// (~8 cyc/stage) instead of ds_swizzle's DS-pipe (~120 cyc/stage).
// Harness-validated correct in rounds 1/3/4 (absmax identical to shfl).
template <int CTRL>
__device__ __forceinline__ float dpp_add(float x) {
  int s = __builtin_amdgcn_update_dpp(0, __float_as_int(x), CTRL, 0xF, 0xF, true);
  return x + __int_as_float(s);
}

// Sum across a 16-lane row (chains are 16 consecutive lanes, row-aligned).
__device__ __forceinline__ float rowsum16(float p) {
  p = dpp_add<0xB1>(p);   // quad_perm [1,0,3,2]  (xor 1)
  p = dpp_add<0x4E>(p);   // quad_perm [2,3,0,1]  (xor 2)
  p = dpp_add<0x124>(p);  // row_ror:4
  p = dpp_add<0x128>(p);  // row_ror:8
  return p;
}

// ---------------------------------------------------------------------------
// k0: dtype detector. Interprets x's first 2048 uint16 as bf16; real bf16
// N(0,1) data decodes ~99.9% into [1e-4,100]; an fp32 bitstream only ~55%.
// flag=1 -> bf16, flag=0 -> fp32.
// ---------------------------------------------------------------------------
__global__ void k0_detect(const void* x, int* flag) {
  __shared__ int cnt;
  if (threadIdx.x == 0) cnt = 0;
  __syncthreads();
  const unsigned short* u = (const unsigned short*)x;
  int good = 0;
  for (int idx = threadIdx.x; idx < 2048; idx += 256) {
    unsigned int bits = ((unsigned int)u[idx]) << 16;
    float f = __uint_as_float(bits);
    float a = fabsf(f);
    if (a == 0.0f || (a > 1e-4f && a < 100.0f)) good++;
  }
  atomicAdd(&cnt, good);
  __syncthreads();
  if (threadIdx.x == 0) *flag = (cnt >= 1536) ? 1 : 0;
}

// ---------------------------------------------------------------------------
// k1: per (b,t) row: f = gelu(x@W_b+b_b); k=f@Wk; v=f@Wv; meta scalars.
// q and f kept only for t=T-1 (only fused[:, -1, :] feeds the head).
// Grid 2048 blocks x 128 threads.
// ---------------------------------------------------------------------------
template <typename T>
__device__ void k1_body(const void* x, const void* W_b, const void* b_b,
                        const void* Wk, const void* Wv, const void* Wq,
                        const void* W_m, const void* b_m,
                        float* kout, float* vout, float* scal4,
                        float* q_last, float* f_last) {
  const int row = blockIdx.x;          // 0..2047
  const int b = row >> 8, t = row & 255;
  const int tid = threadIdx.x;         // 0..127
  __shared__ float xs[DIN];
  __shared__ float fs[DD];
  if (tid < DIN) xs[tid] = getv<T>(x, row * DIN + tid);
  __syncthreads();

  float acc = getv<T>(b_b, tid);
#pragma unroll 8
  for (int d = 0; d < DIN; ++d) acc += xs[d] * getv<T>(W_b, d * DD + tid);
  float f = gelu_tanh(acc);
  fs[tid] = f;
  __syncthreads();

  float ak = 0.0f, av = 0.0f;
#pragma unroll 8
  for (int c = 0; c < DD; ++c) {
    float fc = fs[c];
    ak += fc * getv<T>(Wk, c * DD + tid);
    av += fc * getv<T>(Wv, c * DD + tid);
  }
  kout[row * DD + tid] = ak;
  vout[row * DD + tid] = av;

  if (t == TT - 1) {
    float aq = 0.0f;
#pragma unroll 8
    for (int c = 0; c < DD; ++c) aq += fs[c] * getv<T>(Wq, c * DD + tid);
    q_last[b * DD + tid] = aq;
    f_last[b * DD + tid] = f;
  }
  if (tid < 4) {
    float val = 0.0f;
    if (tid < 3) {
      float a = getv<T>(b_m, tid);
      for (int c = 0; c < DD; ++c) a += fs[c] * getv<T>(W_m, c * 3 + tid);
      float s = sigmoidf(a);
      val = (tid == 0) ? 0.01f * s : ((tid == 1) ? s : 0.1f * s);
    }
    scal4[row * 4 + tid] = val;  // (theta, eta, alpha, 0)
  }
}

__global__ __launch_bounds__(128) void k1_kern(
    const void* x, const void* W_b, const void* b_b, const void* Wk,
    const void* Wv, const void* Wq, const void* W_m, const void* b_m,
    const int* flag, float* kout, float* vout, float* scal4, float* q_last,
    float* f_last) {
  if (*flag)
    k1_body<__hip_bfloat16>(x, W_b, b_b, Wk, Wv, Wq, W_m, b_m, kout, vout,
                            scal4, q_last, f_last);
  else
    k1_body<float>(x, W_b, b_b, Wk, Wv, Wq, W_m, b_m, kout, vout, scal4,
                   q_last, f_last);
}

// ---------------------------------------------------------------------------
// k2: the scan. 1024 independent row-chains (b,i); one chain = 16 lanes,
// 8 fp32 M + 8 fp32 S elems per lane in registers.
//
// Lever history (each tested in isolation):
//  - r3: DPP reduce (vs ds_swizzle): validated, kept.
//  - r4: geometry 256 blk x 64 thr = 1 wave/CU on all 256 CUs: 782->520
//    cyc/step. FETCH 8.4MB = 8x working set (per-XCD L2 copies) -> first
//    toucher pays ~HBM latency; 1-ahead prefetch (~130cyc cover) leaves
//    ~400cyc/step exposed.
//  - r5 (this): ONLY change = pipeline depth 1 -> 4 (named slots, static
//    indexing). 16 loads in flight, counted vmcnt waits; 4 steps of compute
//    (~520cyc) cover HBM-class latency. Chain floor ~100cyc/step.
//    (r1's depth-4 regression was confounded by same-b-same-XCD mapping +
//    64-CU packing; this is the clean depth test.)
// All 4 chains of a wave share b -> kp base is wave-uniform (SGPR).
// ---------------------------------------------------------------------------
__global__ __launch_bounds__(64) void k2_scan(
    const float* __restrict__ kbuf, const float* __restrict__ vbuf,
    const float* __restrict__ scal, const float* __restrict__ q_last,
    float* __restrict__ m_last) {
  const int tid = threadIdx.x;
  const int g = tid & 15;
  const int chain = blockIdx.x * 4 + (tid >> 4);  // 0..1023
  const int b = chain >> 7;
  const int i = chain & 127;

  const float4* kp = (const float4*)(kbuf + (size_t)b * TT * DD) + (g << 1);
  const float* vp = vbuf + (size_t)b * TT * DD + i;
  const float4* sp = (const float4*)(scal) + b * TT;

  float4 Ma = {0, 0, 0, 0}, Mb = {0, 0, 0, 0};
  float4 Sa = {0, 0, 0, 0}, Sb = {0, 0, 0, 0};

  // 4-deep pipeline: explicit named slots (compile-time indexing only).
  float4 ka0 = kp[0 * 32], kb0 = kp[0 * 32 + 1], sc0 = sp[0];
  float4 ka1 = kp[1 * 32], kb1 = kp[1 * 32 + 1], sc1 = sp[1];
  float4 ka2 = kp[2 * 32], kb2 = kp[2 * 32 + 1], sc2 = sp[2];
  float4 ka3 = kp[3 * 32], kb3 = kp[3 * 32 + 1], sc3 = sp[3];
  float v0 = vp[0 * 128], v1 = vp[1 * 128], v2 = vp[2 * 128], v3 = vp[3 * 128];

#define K2_STEP(KA, KB, VV, SC)                                              \
  {                                                                          \
    float p = (Ma.x * KA.x + Ma.y * KA.y) + (Ma.z * KA.z + Ma.w * KA.w) +    \
              (Mb.x * KB.x + Mb.y * KB.y) + (Mb.z * KB.z + Mb.w * KB.w);     \
    p = rowsum16(p);                                                         \
    const float err = p - VV;                                                \
    const float c = SC.x * err;   /* theta * err */                          \
    const float et = SC.y;        /* eta */                                  \
    const float am = 1.0f - SC.z; /* 1 - alpha */                            \
    Sa.x = et * Sa.x - c * KA.x;  Ma.x = am * Ma.x + Sa.x;                   \
    Sa.y = et * Sa.y - c * KA.y;  Ma.y = am * Ma.y + Sa.y;                   \
    Sa.z = et * Sa.z - c * KA.z;  Ma.z = am * Ma.z + Sa.z;                   \
    Sa.w = et * Sa.w - c * KA.w;  Ma.w = am * Ma.w + Sa.w;                   \
    Sb.x = et * Sb.x - c * KB.x;  Mb.x = am * Mb.x + Sb.x;                   \
    Sb.y = et * Sb.y - c * KB.y;  Mb.y = am * Mb.y + Sb.y;                   \
    Sb.z = et * Sb.z - c * KB.z;  Mb.z = am * Mb.z + Sb.z;                   \
    Sb.w = et * Sb.w - c * KB.w;  Mb.w = am * Mb.w + Sb.w;                   \
  }

#define K2_REFILL(SLOT_KA, SLOT_KB, SLOT_V, SLOT_SC, TN)                     \
  {                                                                          \
    const int tn = (TN) & (TT - 1); /* wraps at end; values unused */        \
    SLOT_KA = kp[tn * 32];                                                   \
    SLOT_KB = kp[tn * 32 + 1];                                               \
    SLOT_V = vp[tn * 128];                                                   \
    SLOT_SC = sp[tn];                                                        \
  }

  for (int t = 0; t < TT; t += 4) {
    K2_STEP(ka0, kb0, v0, sc0);
    K2_REFILL(ka0, kb0, v0, sc0, t + 4);
    K2_STEP(ka1, kb1, v1, sc1);
    K2_REFILL(ka1, kb1, v1, sc1, t + 5);
    K2_STEP(ka2, kb2, v2, sc2);
    K2_REFILL(ka2, kb2, v2, sc2, t + 6);
    K2_STEP(ka3, kb3, v3, sc3);
    K2_REFILL(ka3, kb3, v3, sc3, t + 7);
  }
#undef K2_STEP
#undef K2_REFILL

  const float4* qp = (const float4*)(q_last + b * DD) + (g << 1);
  float4 qa = qp[0], qb = qp[1];
  float p = (Ma.x * qa.x + Ma.y * qa.y) + (Ma.z * qa.z + Ma.w * qa.w) +
            (Mb.x * qb.x + Mb.y * qb.y) + (Mb.z * qb.z + Mb.w * qb.w);
  p = rowsum16(p);
  if (g == 0) m_last[b * DD + i] = p;
}

// ---------------------------------------------------------------------------
// k3: head. gate -> fused -> W1+LN+gelu -> W2. 8 blocks x 256 threads.
// ---------------------------------------------------------------------------
template <typename T>
__device__ void k3_body(const float* f_last, const float* m_last,
                        const void* W_f, const void* b_f, const void* W1,
                        const void* b1, const void* g1, const void* be1,
                        const void* W2, const void* b2, void* out) {
  const int b = blockIdx.x, tid = threadIdx.x;
  __shared__ float fm[2 * DD];
  __shared__ float fused[DD];
  __shared__ float tmp[DD];
  __shared__ float h[DD];
  __shared__ float smu, srs;

  fm[tid] = (tid < DD) ? f_last[b * DD + tid] : m_last[b * DD + tid - DD];
  __syncthreads();

  if (tid < DD) {
    float a = getv<T>(b_f, tid);
#pragma unroll 8
    for (int c = 0; c < 2 * DD; ++c) a += fm[c] * getv<T>(W_f, c * DD + tid);
    float gte = sigmoidf(a);
    fused[tid] = fm[tid] * gte + fm[DD + tid] * (1.0f - gte);
  }
  __syncthreads();

  if (tid < DD) {
    float a = getv<T>(b1, tid);
#pragma unroll 8
    for (int c = 0; c < DD; ++c) a += fused[c] * getv<T>(W1, c * DD + tid);
    tmp[tid] = a;
  }
  __syncthreads();

  if (tid == 0) {
    float s = 0.0f;
    for (int c = 0; c < DD; ++c) s += tmp[c];
    float mu = s / (float)DD;
    float s2 = 0.0f;
    for (int c = 0; c < DD; ++c) {
      float d = tmp[c] - mu;
      s2 += d * d;
    }
    smu = mu;
    srs = rsqrtf(s2 / (float)DD + 1e-5f);
  }
  __syncthreads();

  if (tid < DD)
    h[tid] = gelu_tanh((tmp[tid] - smu) * srs * getv<T>(g1, tid) +
                       getv<T>(be1, tid));
  __syncthreads();

  for (int j = tid; j < 672; j += 256) {
    float a = getv<T>(b2, j);
#pragma unroll 8
    for (int c = 0; c < DD; ++c) a += h[c] * getv<T>(W2, c * 672 + j);
    if (sizeof(T) == 2)
      ((__hip_bfloat16*)out)[b * 672 + j] = __float2bfloat16(a);
    else
      ((float*)out)[b * 672 + j] = a;
  }
}

__global__ __launch_bounds__(256) void k3_kern(
    const float* f_last, const float* m_last, const void* W_f,
    const void* b_f, const void* W1, const void* b1, const void* g1,
    const void* be1, const void* W2, const void* b2, const int* flag,
    void* out) {
  if (*flag)
    k3_body<__hip_bfloat16>(f_last, m_last, W_f, b_f, W1, b1, g1, be1, W2, b2,
                            out);
  else
    k3_body<float>(f_last, m_last, W_f, b_f, W1, b1, g1, be1, W2, b2, out);
}

// ---------------------------------------------------------------------------
extern "C" void kernel_launch(void* const* d_in, const int* in_sizes, int n_in,
                              void* d_out, int out_size, void* d_ws,
                              size_t ws_size, hipStream_t stream) {
  const void* x   = d_in[0];
  const void* W_b = d_in[1];
  const void* b_b = d_in[2];
  const void* Wk  = d_in[3];
  const void* Wv  = d_in[4];
  const void* Wq  = d_in[5];
  const void* W_m = d_in[6];
  const void* b_m = d_in[7];
  const void* W_f = d_in[8];
  const void* b_f = d_in[9];
  const void* W1  = d_in[10];
  const void* b1  = d_in[11];
  const void* g1  = d_in[12];
  const void* be1 = d_in[13];
  const void* W2  = d_in[14];
  const void* b2  = d_in[15];

  float* w = (float*)d_ws;
  float* kbuf   = w;                    // 262144
  float* vbuf   = w + 262144;           // 262144
  float* scal4  = w + 524288;           // 8192  (theta,eta,alpha,0) per (b,t)
  float* q_last = w + 532480;           // 1024
  float* f_last = w + 533504;           // 1024
  float* m_last = w + 534528;           // 1024
  int*   flag   = (int*)(w + 535552);

  k0_detect<<<1, 256, 0, stream>>>(x, flag);
  k1_kern<<<BB * TT, 128, 0, stream>>>(x, W_b, b_b, Wk, Wv, Wq, W_m, b_m,
                                       flag, kbuf, vbuf, scal4, q_last,
                                       f_last);
  k2_scan<<<256, 64, 0, stream>>>(kbuf, vbuf, scal4, q_last, m_last);
  k3_kern<<<BB, 256, 0, stream>>>(f_last, m_last, W_f, b_f, W1, b1, g1, be1,
                                  W2, b2, flag, d_out);
}

// Round 6
// 178.974 us; speedup vs baseline: 1.1926x; 1.1926x over previous
//
#include <hip/hip_runtime.h>
#include <hip/hip_bf16.h>

#define BB 8
#define TT 256
#define DIN 64
#define DD 128

__device__ __forceinline__ float gelu_tanh(float x) {
  float x3 = x * x * x;
  return 0.5f * x * (1.0f + tanhf(0.7978845608028654f * (x + 0.044715f * x3)));
}
__device__ __forceinline__ float sigmoidf(float x) {
  return 1.0f / (1.0f + __expf(-x));
}

template <typename T> __device__ __forceinline__ float getv(const void* p, int i);
template <> __device__ __forceinline__ float getv<float>(const void* p, int i) {
  return ((const float*)p)[i];
}
template <> __device__ __forceinline__ float getv<__hip_bfloat16>(const void* p, int i) {
  return __bfloat162float(((const __hip_bfloat16*)p)[i]);
}

// DPP-based add from a statically-controlled source lane. All-VALU.
// Harness-validated correct in rounds 1/3/4/5.
template <int CTRL>
__device__ __forceinline__ float dpp_add(float x) {
  int s = __builtin_amdgcn_update_dpp(0, __float_as_int(x), CTRL, 0xF, 0xF, true);
  return x + __int_as_float(s);
}

// Sum across a 16-lane row (chains are 16 consecutive lanes, row-aligned).
__device__ __forceinline__ float rowsum16(float p) {
  p = dpp_add<0xB1>(p);   // quad_perm [1,0,3,2]  (xor 1)
  p = dpp_add<0x4E>(p);   // quad_perm [2,3,0,1]  (xor 2)
  p = dpp_add<0x124>(p);  // row_ror:4
  p = dpp_add<0x128>(p);  // row_ror:8
  return p;
}

// Async global->LDS, 16B per lane. LDS dest is wave-uniform base + lane*16;
// global src is per-lane. Tracked by vmcnt.
__device__ __forceinline__ void gload_lds16(const void* g, void* l) {
  __builtin_amdgcn_global_load_lds(
      (const __attribute__((address_space(1))) void*)g,
      (__attribute__((address_space(3))) void*)l, 16, 0, 0);
}

// ---------------------------------------------------------------------------
// k0: dtype detector (bf16 vs fp32 input bitstream). flag=1 -> bf16.
// ---------------------------------------------------------------------------
__global__ void k0_detect(const void* x, int* flag) {
  __shared__ int cnt;
  if (threadIdx.x == 0) cnt = 0;
  __syncthreads();
  const unsigned short* u = (const unsigned short*)x;
  int good = 0;
  for (int idx = threadIdx.x; idx < 2048; idx += 256) {
    unsigned int bits = ((unsigned int)u[idx]) << 16;
    float f = __uint_as_float(bits);
    float a = fabsf(f);
    if (a == 0.0f || (a > 1e-4f && a < 100.0f)) good++;
  }
  atomicAdd(&cnt, good);
  __syncthreads();
  if (threadIdx.x == 0) *flag = (cnt >= 1536) ? 1 : 0;
}

// ---------------------------------------------------------------------------
// k1: per (b,t) row: f = gelu(x@W_b+b_b); k=f@Wk; v=f@Wv; meta scalars.
// ---------------------------------------------------------------------------
template <typename T>
__device__ void k1_body(const void* x, const void* W_b, const void* b_b,
                        const void* Wk, const void* Wv, const void* Wq,
                        const void* W_m, const void* b_m,
                        float* kout, float* vout, float* scal4,
                        float* q_last, float* f_last) {
  const int row = blockIdx.x;          // 0..2047
  const int b = row >> 8, t = row & 255;
  const int tid = threadIdx.x;         // 0..127
  __shared__ float xs[DIN];
  __shared__ float fs[DD];
  if (tid < DIN) xs[tid] = getv<T>(x, row * DIN + tid);
  __syncthreads();

  float acc = getv<T>(b_b, tid);
#pragma unroll 8
  for (int d = 0; d < DIN; ++d) acc += xs[d] * getv<T>(W_b, d * DD + tid);
  float f = gelu_tanh(acc);
  fs[tid] = f;
  __syncthreads();

  float ak = 0.0f, av = 0.0f;
#pragma unroll 8
  for (int c = 0; c < DD; ++c) {
    float fc = fs[c];
    ak += fc * getv<T>(Wk, c * DD + tid);
    av += fc * getv<T>(Wv, c * DD + tid);
  }
  kout[row * DD + tid] = ak;
  vout[row * DD + tid] = av;

  if (t == TT - 1) {
    float aq = 0.0f;
#pragma unroll 8
    for (int c = 0; c < DD; ++c) aq += fs[c] * getv<T>(Wq, c * DD + tid);
    q_last[b * DD + tid] = aq;
    f_last[b * DD + tid] = f;
  }
  if (tid < 4) {
    float val = 0.0f;
    if (tid < 3) {
      float a = getv<T>(b_m, tid);
      for (int c = 0; c < DD; ++c) a += fs[c] * getv<T>(W_m, c * 3 + tid);
      float s = sigmoidf(a);
      val = (tid == 0) ? 0.01f * s : ((tid == 1) ? s : 0.1f * s);
    }
    scal4[row * 4 + tid] = val;  // (theta, eta, alpha, 0)
  }
}

__global__ __launch_bounds__(128) void k1_kern(
    const void* x, const void* W_b, const void* b_b, const void* Wk,
    const void* Wv, const void* Wq, const void* W_m, const void* b_m,
    const int* flag, float* kout, float* vout, float* scal4, float* q_last,
    float* f_last) {
  if (*flag)
    k1_body<__hip_bfloat16>(x, W_b, b_b, Wk, Wv, Wq, W_m, b_m, kout, vout,
                            scal4, q_last, f_last);
  else
    k1_body<float>(x, W_b, b_b, Wk, Wv, Wq, W_m, b_m, kout, vout, scal4,
                   q_last, f_last);
}

// ---------------------------------------------------------------------------
// k2: the scan. 1024 chains; one chain = 16 lanes; 4 chains (one b) per
// block; 256 blocks x 64 threads = 1 wave/CU (r4-validated geometry).
//
// Lever history:
//  - r3 DPP reduce: validated, kept.  r4 geometry: validated, kept.
//  - r5 register SWP depth-4: REGRESSED (compiler vmcnt placement) - dead.
//  - r6 (this): LDS chunk double-buffer. k staged in 16KB/32-step chunks via
//    global_load_lds (async, vmcnt); ONE manual vmcnt(0) per 32 steps with
//    nothing else outstanding -> deterministic wait. v/sc fully preloaded to
//    LDS. Loop reads LDS only (1-ahead, ~120cyc hidden under ~150cyc VALU).
//    Lock-step HBM first-toucher latency (~370cyc/step exposed at r4) now
//    amortized: 16 loads per ~6000cyc of compute cover.
// ---------------------------------------------------------------------------
__global__ __launch_bounds__(64) void k2_scan(
    const float* __restrict__ kbuf, const float* __restrict__ vbuf,
    const float* __restrict__ scal, const float* __restrict__ q_last,
    float* __restrict__ m_last) {
  const int tid = threadIdx.x;         // 0..63
  const int g = tid & 15;
  const int cidx = tid >> 4;           // chain-in-block 0..3
  const int chain = blockIdx.x * 4 + cidx;
  const int b = chain >> 7;
  const int i = chain & 127;
  const int i0 = (blockIdx.x * 4) & 127;  // first chain's column

  __shared__ float kl[2][32 * DD];     // 2 x 16KB k chunks (32 t-rows each)
  __shared__ float vl[TT * 4];         // v[t][c] for this block's 4 chains
  __shared__ float4 scl[TT];           // (theta,eta,alpha,0) per t

  const float* kslice = kbuf + (size_t)b * TT * DD;
  const float* vslice = vbuf + (size_t)b * TT * DD;

  // ---- prologue: preload v (gather) and sc (coalesced) into LDS ----
  for (int idx = tid; idx < TT * 4; idx += 64)
    vl[idx] = vslice[(idx >> 2) * DD + i0 + (idx & 3)];
  const float4* sp4 = (const float4*)scal + b * TT;
  for (int idx = tid; idx < TT; idx += 64) scl[idx] = sp4[idx];

  // ---- issue chunk 0 (16 x 1KB async copies) ----
#define K2_GLL(CH, BUF)                                                      \
  {                                                                          \
    const float* gs = kslice + (CH) * 32 * DD + tid * 4;                     \
    _Pragma("unroll") for (int j = 0; j < 16; ++j)                           \
        gload_lds16(gs + j * 256, &kl[BUF][j * 256]);                        \
  }
  K2_GLL(0, 0);

  float4 Ma = {0, 0, 0, 0}, Mb = {0, 0, 0, 0};
  float4 Sa = {0, 0, 0, 0}, Sb = {0, 0, 0, 0};

#define K2_STEP(KA, KB, VV, SC)                                              \
  {                                                                          \
    float p = (Ma.x * KA.x + Ma.y * KA.y) + (Ma.z * KA.z + Ma.w * KA.w) +    \
              (Mb.x * KB.x + Mb.y * KB.y) + (Mb.z * KB.z + Mb.w * KB.w);     \
    p = rowsum16(p);                                                         \
    const float err = p - VV;                                                \
    const float c = SC.x * err;   /* theta * err */                          \
    const float et = SC.y;        /* eta */                                  \
    const float am = 1.0f - SC.z; /* 1 - alpha */                            \
    Sa.x = et * Sa.x - c * KA.x;  Ma.x = am * Ma.x + Sa.x;                   \
    Sa.y = et * Sa.y - c * KA.y;  Ma.y = am * Ma.y + Sa.y;                   \
    Sa.z = et * Sa.z - c * KA.z;  Ma.z = am * Ma.z + Sa.z;                   \
    Sa.w = et * Sa.w - c * KA.w;  Ma.w = am * Ma.w + Sa.w;                   \
    Sb.x = et * Sb.x - c * KB.x;  Mb.x = am * Mb.x + Sb.x;                   \
    Sb.y = et * Sb.y - c * KB.y;  Mb.y = am * Mb.y + Sb.y;                   \
    Sb.z = et * Sb.z - c * KB.z;  Mb.z = am * Mb.z + Sb.z;                   \
    Sb.w = et * Sb.w - c * KB.w;  Mb.w = am * Mb.w + Sb.w;                   \
  }

  for (int ch = 0; ch < 8; ++ch) {
    // current chunk's async copies (issued one chunk ago, or just above for
    // ch=0) are the ONLY outstanding vmem; drain them. lgkm for ds_writes.
    asm volatile("s_waitcnt vmcnt(0) lgkmcnt(0)" ::: "memory");
    if (ch < 7) K2_GLL(ch + 1, (ch + 1) & 1);  // next chunk: ~6000cyc cover

    const float* kc = &kl[ch & 1][0];
    const int tbase = ch * 32;

    float4 ka = *(const float4*)(kc + g * 8);
    float4 kb = *(const float4*)(kc + g * 8 + 4);
    float vv = vl[tbase * 4 + cidx];
    float4 sc = scl[tbase];

#pragma unroll
    for (int tt = 0; tt < 32; ++tt) {
      float4 nka, nkb, nsc;
      float nv;
      if (tt < 31) {  // 1-ahead LDS prefetch (within chunk)
        nka = *(const float4*)(kc + (tt + 1) * DD + g * 8);
        nkb = *(const float4*)(kc + (tt + 1) * DD + g * 8 + 4);
        nv = vl[(tbase + tt + 1) * 4 + cidx];
        nsc = scl[tbase + tt + 1];
      }
      K2_STEP(ka, kb, vv, sc);
      if (tt < 31) { ka = nka; kb = nkb; vv = nv; sc = nsc; }
    }
  }
#undef K2_STEP
#undef K2_GLL

  const float4* qp = (const float4*)(q_last + b * DD) + (g << 1);
  float4 qa = qp[0], qb = qp[1];
  float p = (Ma.x * qa.x + Ma.y * qa.y) + (Ma.z * qa.z + Ma.w * qa.w) +
            (Mb.x * qb.x + Mb.y * qb.y) + (Mb.z * qb.z + Mb.w * qb.w);
  p = rowsum16(p);
  if (g == 0) m_last[b * DD + i] = p;
}

// ---------------------------------------------------------------------------
// k3: head. gate -> fused -> W1+LN+gelu -> W2. 8 blocks x 256 threads.
// ---------------------------------------------------------------------------
template <typename T>
__device__ void k3_body(const float* f_last, const float* m_last,
                        const void* W_f, const void* b_f, const void* W1,
                        const void* b1, const void* g1, const void* be1,
                        const void* W2, const void* b2, void* out) {
  const int b = blockIdx.x, tid = threadIdx.x;
  __shared__ float fm[2 * DD];
  __shared__ float fused[DD];
  __shared__ float tmp[DD];
  __shared__ float h[DD];
  __shared__ float smu, srs;

  fm[tid] = (tid < DD) ? f_last[b * DD + tid] : m_last[b * DD + tid - DD];
  __syncthreads();

  if (tid < DD) {
    float a = getv<T>(b_f, tid);
#pragma unroll 8
    for (int c = 0; c < 2 * DD; ++c) a += fm[c] * getv<T>(W_f, c * DD + tid);
    float gte = sigmoidf(a);
    fused[tid] = fm[tid] * gte + fm[DD + tid] * (1.0f - gte);
  }
  __syncthreads();

  if (tid < DD) {
    float a = getv<T>(b1, tid);
#pragma unroll 8
    for (int c = 0; c < DD; ++c) a += fused[c] * getv<T>(W1, c * DD + tid);
    tmp[tid] = a;
  }
  __syncthreads();

  if (tid == 0) {
    float s = 0.0f;
    for (int c = 0; c < DD; ++c) s += tmp[c];
    float mu = s / (float)DD;
    float s2 = 0.0f;
    for (int c = 0; c < DD; ++c) {
      float d = tmp[c] - mu;
      s2 += d * d;
    }
    smu = mu;
    srs = rsqrtf(s2 / (float)DD + 1e-5f);
  }
  __syncthreads();

  if (tid < DD)
    h[tid] = gelu_tanh((tmp[tid] - smu) * srs * getv<T>(g1, tid) +
                       getv<T>(be1, tid));
  __syncthreads();

  for (int j = tid; j < 672; j += 256) {
    float a = getv<T>(b2, j);
#pragma unroll 8
    for (int c = 0; c < DD; ++c) a += h[c] * getv<T>(W2, c * 672 + j);
    if (sizeof(T) == 2)
      ((__hip_bfloat16*)out)[b * 672 + j] = __float2bfloat16(a);
    else
      ((float*)out)[b * 672 + j] = a;
  }
}

__global__ __launch_bounds__(256) void k3_kern(
    const float* f_last, const float* m_last, const void* W_f,
    const void* b_f, const void* W1, const void* b1, const void* g1,
    const void* be1, const void* W2, const void* b2, const int* flag,
    void* out) {
  if (*flag)
    k3_body<__hip_bfloat16>(f_last, m_last, W_f, b_f, W1, b1, g1, be1, W2, b2,
                            out);
  else
    k3_body<float>(f_last, m_last, W_f, b_f, W1, b1, g1, be1, W2, b2, out);
}

// ---------------------------------------------------------------------------
extern "C" void kernel_launch(void* const* d_in, const int* in_sizes, int n_in,
                              void* d_out, int out_size, void* d_ws,
                              size_t ws_size, hipStream_t stream) {
  const void* x   = d_in[0];
  const void* W_b = d_in[1];
  const void* b_b = d_in[2];
  const void* Wk  = d_in[3];
  const void* Wv  = d_in[4];
  const void* Wq  = d_in[5];
  const void* W_m = d_in[6];
  const void* b_m = d_in[7];
  const void* W_f = d_in[8];
  const void* b_f = d_in[9];
  const void* W1  = d_in[10];
  const void* b1  = d_in[11];
  const void* g1  = d_in[12];
  const void* be1 = d_in[13];
  const void* W2  = d_in[14];
  const void* b2  = d_in[15];

  float* w = (float*)d_ws;
  float* kbuf   = w;                    // 262144
  float* vbuf   = w + 262144;           // 262144
  float* scal4  = w + 524288;           // 8192  (theta,eta,alpha,0) per (b,t)
  float* q_last = w + 532480;           // 1024
  float* f_last = w + 533504;           // 1024
  float* m_last = w + 534528;           // 1024
  int*   flag   = (int*)(w + 535552);

  k0_detect<<<1, 256, 0, stream>>>(x, flag);
  k1_kern<<<BB * TT, 128, 0, stream>>>(x, W_b, b_b, Wk, Wv, Wq, W_m, b_m,
                                       flag, kbuf, vbuf, scal4, q_last,
                                       f_last);
  k2_scan<<<256, 64, 0, stream>>>(kbuf, vbuf, scal4, q_last, m_last);
  k3_kern<<<BB, 256, 0, stream>>>(f_last, m_last, W_f, b_f, W1, b1, g1, be1,
                                  W2, b2, flag, d_out);
}

// Round 7
// 154.437 us; speedup vs baseline: 1.3821x; 1.1589x over previous
//
#include <hip/hip_runtime.h>
#include <hip/hip_bf16.h>

#define BB 8
#define TT 256
#define DIN 64
#define DD 128

__device__ __forceinline__ float gelu_tanh(float x) {
  float x3 = x * x * x;
  return 0.5f * x * (1.0f + tanhf(0.7978845608028654f * (x + 0.044715f * x3)));
}
__device__ __forceinline__ float sigmoidf(float x) {
  return 1.0f / (1.0f + __expf(-x));
}

template <typename T> __device__ __forceinline__ float getv(const void* p, int i);
template <> __device__ __forceinline__ float getv<float>(const void* p, int i) {
  return ((const float*)p)[i];
}
template <> __device__ __forceinline__ float getv<__hip_bfloat16>(const void* p, int i) {
  return __bfloat162float(((const __hip_bfloat16*)p)[i]);
}

// DPP-based add from a statically-controlled source lane. All-VALU.
// Harness-validated correct in rounds 1/3/4/5/6.
template <int CTRL>
__device__ __forceinline__ float dpp_add(float x) {
  int s = __builtin_amdgcn_update_dpp(0, __float_as_int(x), CTRL, 0xF, 0xF, true);
  return x + __int_as_float(s);
}

// Sum across a 16-lane row.
__device__ __forceinline__ float rowsum16(float p) {
  p = dpp_add<0xB1>(p);   // quad_perm [1,0,3,2]  (xor 1)
  p = dpp_add<0x4E>(p);   // quad_perm [2,3,0,1]  (xor 2)
  p = dpp_add<0x124>(p);  // row_ror:4
  p = dpp_add<0x128>(p);  // row_ror:8
  return p;
}

// Async global->LDS, 16B per lane. LDS dest is wave-uniform base + lane*16;
// global src is per-lane. Tracked by vmcnt. (r6-validated)
__device__ __forceinline__ void gload_lds16(const void* g, void* l) {
  __builtin_amdgcn_global_load_lds(
      (const __attribute__((address_space(1))) void*)g,
      (__attribute__((address_space(3))) void*)l, 16, 0, 0);
}

// ---------------------------------------------------------------------------
// k0: dtype detector (bf16 vs fp32 input bitstream). flag=1 -> bf16.
// ---------------------------------------------------------------------------
__global__ void k0_detect(const void* x, int* flag) {
  __shared__ int cnt;
  if (threadIdx.x == 0) cnt = 0;
  __syncthreads();
  const unsigned short* u = (const unsigned short*)x;
  int good = 0;
  for (int idx = threadIdx.x; idx < 2048; idx += 256) {
    unsigned int bits = ((unsigned int)u[idx]) << 16;
    float f = __uint_as_float(bits);
    float a = fabsf(f);
    if (a == 0.0f || (a > 1e-4f && a < 100.0f)) good++;
  }
  atomicAdd(&cnt, good);
  __syncthreads();
  if (threadIdx.x == 0) *flag = (cnt >= 1536) ? 1 : 0;
}

// ---------------------------------------------------------------------------
// k1: per (b,t) row: f = gelu(x@W_b+b_b); k=f@Wk; v=f@Wv; meta scalars.
// ---------------------------------------------------------------------------
template <typename T>
__device__ void k1_body(const void* x, const void* W_b, const void* b_b,
                        const void* Wk, const void* Wv, const void* Wq,
                        const void* W_m, const void* b_m,
                        float* kout, float* vout, float* scal4,
                        float* q_last, float* f_last) {
  const int row = blockIdx.x;          // 0..2047
  const int b = row >> 8, t = row & 255;
  const int tid = threadIdx.x;         // 0..127
  __shared__ float xs[DIN];
  __shared__ float fs[DD];
  if (tid < DIN) xs[tid] = getv<T>(x, row * DIN + tid);
  __syncthreads();

  float acc = getv<T>(b_b, tid);
#pragma unroll 8
  for (int d = 0; d < DIN; ++d) acc += xs[d] * getv<T>(W_b, d * DD + tid);
  float f = gelu_tanh(acc);
  fs[tid] = f;
  __syncthreads();

  float ak = 0.0f, av = 0.0f;
#pragma unroll 8
  for (int c = 0; c < DD; ++c) {
    float fc = fs[c];
    ak += fc * getv<T>(Wk, c * DD + tid);
    av += fc * getv<T>(Wv, c * DD + tid);
  }
  kout[row * DD + tid] = ak;
  vout[row * DD + tid] = av;

  if (t == TT - 1) {
    float aq = 0.0f;
#pragma unroll 8
    for (int c = 0; c < DD; ++c) aq += fs[c] * getv<T>(Wq, c * DD + tid);
    q_last[b * DD + tid] = aq;
    f_last[b * DD + tid] = f;
  }
  if (tid < 4) {
    float val = 0.0f;
    if (tid < 3) {
      float a = getv<T>(b_m, tid);
      for (int c = 0; c < DD; ++c) a += fs[c] * getv<T>(W_m, c * 3 + tid);
      float s = sigmoidf(a);
      val = (tid == 0) ? 0.01f * s : ((tid == 1) ? s : 0.1f * s);
    }
    scal4[row * 4 + tid] = val;  // (theta, eta, alpha, 0)
  }
}

__global__ __launch_bounds__(128) void k1_kern(
    const void* x, const void* W_b, const void* b_b, const void* Wk,
    const void* Wv, const void* Wq, const void* W_m, const void* b_m,
    const int* flag, float* kout, float* vout, float* scal4, float* q_last,
    float* f_last) {
  if (*flag)
    k1_body<__hip_bfloat16>(x, W_b, b_b, Wk, Wv, Wq, W_m, b_m, kout, vout,
                            scal4, q_last, f_last);
  else
    k1_body<float>(x, W_b, b_b, Wk, Wv, Wq, W_m, b_m, kout, vout, scal4,
                   q_last, f_last);
}

// ---------------------------------------------------------------------------
// k2: the scan (r6 structure, validated: LDS chunk double-buffer via
// global_load_lds, one manual vmcnt(0) per 32 steps, DPP reduce,
// 256 blocks x 64 threads = 1 wave/CU).
// ---------------------------------------------------------------------------
__global__ __launch_bounds__(64) void k2_scan(
    const float* __restrict__ kbuf, const float* __restrict__ vbuf,
    const float* __restrict__ scal, const float* __restrict__ q_last,
    float* __restrict__ m_last) {
  const int tid = threadIdx.x;         // 0..63
  const int g = tid & 15;
  const int cidx = tid >> 4;           // chain-in-block 0..3
  const int chain = blockIdx.x * 4 + cidx;
  const int b = chain >> 7;
  const int i = chain & 127;
  const int i0 = (blockIdx.x * 4) & 127;  // first chain's column

  __shared__ float kl[2][32 * DD];     // 2 x 16KB k chunks (32 t-rows each)
  __shared__ float vl[TT * 4];         // v[t][c] for this block's 4 chains
  __shared__ float4 scl[TT];           // (theta,eta,alpha,0) per t

  const float* kslice = kbuf + (size_t)b * TT * DD;
  const float* vslice = vbuf + (size_t)b * TT * DD;

  // ---- prologue: preload v (gather) and sc (coalesced) into LDS ----
  for (int idx = tid; idx < TT * 4; idx += 64)
    vl[idx] = vslice[(idx >> 2) * DD + i0 + (idx & 3)];
  const float4* sp4 = (const float4*)scal + b * TT;
  for (int idx = tid; idx < TT; idx += 64) scl[idx] = sp4[idx];

#define K2_GLL(CH, BUF)                                                      \
  {                                                                          \
    const float* gs = kslice + (CH) * 32 * DD + tid * 4;                     \
    _Pragma("unroll") for (int j = 0; j < 16; ++j)                           \
        gload_lds16(gs + j * 256, &kl[BUF][j * 256]);                        \
  }
  K2_GLL(0, 0);

  float4 Ma = {0, 0, 0, 0}, Mb = {0, 0, 0, 0};
  float4 Sa = {0, 0, 0, 0}, Sb = {0, 0, 0, 0};

#define K2_STEP(KA, KB, VV, SC)                                              \
  {                                                                          \
    float p = (Ma.x * KA.x + Ma.y * KA.y) + (Ma.z * KA.z + Ma.w * KA.w) +    \
              (Mb.x * KB.x + Mb.y * KB.y) + (Mb.z * KB.z + Mb.w * KB.w);     \
    p = rowsum16(p);                                                         \
    const float err = p - VV;                                                \
    const float c = SC.x * err;   /* theta * err */                          \
    const float et = SC.y;        /* eta */                                  \
    const float am = 1.0f - SC.z; /* 1 - alpha */                            \
    Sa.x = et * Sa.x - c * KA.x;  Ma.x = am * Ma.x + Sa.x;                   \
    Sa.y = et * Sa.y - c * KA.y;  Ma.y = am * Ma.y + Sa.y;                   \
    Sa.z = et * Sa.z - c * KA.z;  Ma.z = am * Ma.z + Sa.z;                   \
    Sa.w = et * Sa.w - c * KA.w;  Ma.w = am * Ma.w + Sa.w;                   \
    Sb.x = et * Sb.x - c * KB.x;  Mb.x = am * Mb.x + Sb.x;                   \
    Sb.y = et * Sb.y - c * KB.y;  Mb.y = am * Mb.y + Sb.y;                   \
    Sb.z = et * Sb.z - c * KB.z;  Mb.z = am * Mb.z + Sb.z;                   \
    Sb.w = et * Sb.w - c * KB.w;  Mb.w = am * Mb.w + Sb.w;                   \
  }

  for (int ch = 0; ch < 8; ++ch) {
    asm volatile("s_waitcnt vmcnt(0) lgkmcnt(0)" ::: "memory");
    if (ch < 7) K2_GLL(ch + 1, (ch + 1) & 1);  // next chunk: ~6000cyc cover

    const float* kc = &kl[ch & 1][0];
    const int tbase = ch * 32;

    float4 ka = *(const float4*)(kc + g * 8);
    float4 kb = *(const float4*)(kc + g * 8 + 4);
    float vv = vl[tbase * 4 + cidx];
    float4 sc = scl[tbase];

#pragma unroll
    for (int tt = 0; tt < 32; ++tt) {
      float4 nka, nkb, nsc;
      float nv;
      if (tt < 31) {  // 1-ahead LDS prefetch (within chunk)
        nka = *(const float4*)(kc + (tt + 1) * DD + g * 8);
        nkb = *(const float4*)(kc + (tt + 1) * DD + g * 8 + 4);
        nv = vl[(tbase + tt + 1) * 4 + cidx];
        nsc = scl[tbase + tt + 1];
      }
      K2_STEP(ka, kb, vv, sc);
      if (tt < 31) { ka = nka; kb = nkb; vv = nv; sc = nsc; }
    }
  }
#undef K2_STEP
#undef K2_GLL

  const float4* qp = (const float4*)(q_last + b * DD) + (g << 1);
  float4 qa = qp[0], qb = qp[1];
  float p = (Ma.x * qa.x + Ma.y * qa.y) + (Ma.z * qa.z + Ma.w * qa.w) +
            (Mb.x * qb.x + Mb.y * qb.y) + (Mb.z * qb.z + Mb.w * qb.w);
  p = rowsum16(p);
  if (g == 0) m_last[b * DD + i] = p;
}

// ---------------------------------------------------------------------------
// k3a: gate -> fused -> W1 -> LN -> gelu -> h_buf. 8 blocks x 1024 threads.
// r7 restructure: old k3 ran on 8 CUs with 256..500-iteration serial global
// load chains per thread (41-50us, VALUBusy 0.1% = pure latency). Every gemv
// is now c-split 8 ways (o=tid&127, s=tid>>7; 32/16 MACs per thread) + LDS
// combine; LN reduce is wave-parallel (dpp+shfl) instead of tid0-serial.
// ---------------------------------------------------------------------------
template <typename T>
__device__ void k3a_body(const float* f_last, const float* m_last,
                         const void* W_f, const void* b_f, const void* W1,
                         const void* b1, const void* g1, const void* be1,
                         float* h_buf) {
  const int b = blockIdx.x, tid = threadIdx.x;
  const int o = tid & 127, s = tid >> 7;  // 8 c-splits
  __shared__ float fm[2 * DD];
  __shared__ float part[1024];
  __shared__ float fused[DD];
  __shared__ float tmp[DD];
  __shared__ float smu, srs;

  if (tid < 2 * DD)
    fm[tid] = (tid < DD) ? f_last[b * DD + tid] : m_last[b * DD + tid - DD];
  __syncthreads();

  // gate gemv: 256 c's, 8 splits x 32
  {
    float a = 0.0f;
#pragma unroll 8
    for (int cc = 0; cc < 32; ++cc) {
      const int c = s * 32 + cc;
      a += fm[c] * getv<T>(W_f, c * DD + o);
    }
    part[tid] = a;
  }
  __syncthreads();
  if (tid < DD) {
    float a = getv<T>(b_f, tid);
#pragma unroll
    for (int ss = 0; ss < 8; ++ss) a += part[ss * DD + tid];
    float gte = sigmoidf(a);
    fused[tid] = fm[tid] * gte + fm[DD + tid] * (1.0f - gte);
  }
  __syncthreads();

  // W1 gemv: 128 c's, 8 splits x 16
  {
    float a = 0.0f;
#pragma unroll
    for (int cc = 0; cc < 16; ++cc) {
      const int c = s * 16 + cc;
      a += fused[c] * getv<T>(W1, c * DD + o);
    }
    part[tid] = a;
  }
  __syncthreads();
  if (tid < DD) {
    float a = getv<T>(b1, tid);
#pragma unroll
    for (int ss = 0; ss < 8; ++ss) a += part[ss * DD + tid];
    tmp[tid] = a;
  }
  __syncthreads();

  // LN stats: wave-parallel reduce over 128 elems (first wave only)
  if (tid < 64) {
    float x0 = tmp[tid], x1 = tmp[tid + 64];
    float sm = x0 + x1;
    float sq = x0 * x0 + x1 * x1;
    sm = rowsum16(sm);                 // within 16-lane rows (VALU)
    sq = rowsum16(sq);
    sm += __shfl_xor(sm, 16); sq += __shfl_xor(sq, 16);
    sm += __shfl_xor(sm, 32); sq += __shfl_xor(sq, 32);
    if (tid == 0) {
      float mu = sm / (float)DD;
      smu = mu;
      srs = rsqrtf(sq / (float)DD - mu * mu + 1e-5f);
    }
  }
  __syncthreads();

  if (tid < DD)
    h_buf[b * DD + tid] = gelu_tanh((tmp[tid] - smu) * srs * getv<T>(g1, tid) +
                                    getv<T>(be1, tid));
}

__global__ __launch_bounds__(1024) void k3a_kern(
    const float* f_last, const float* m_last, const void* W_f,
    const void* b_f, const void* W1, const void* b1, const void* g1,
    const void* be1, const int* flag, float* h_buf) {
  if (*flag)
    k3a_body<__hip_bfloat16>(f_last, m_last, W_f, b_f, W1, b1, g1, be1, h_buf);
  else
    k3a_body<float>(f_last, m_last, W_f, b_f, W1, b1, g1, be1, h_buf);
}

// ---------------------------------------------------------------------------
// k3b: out = h @ W2 + b2. 88 blocks (8 b x 11 j-chunks) x 256 threads.
// Threads = 64 j (fast; wave reads 256B contiguous W2) x 4 c-splits of 32.
// ---------------------------------------------------------------------------
template <typename T>
__device__ void k3b_body(const float* h_buf, const void* W2, const void* b2,
                         void* out) {
  const int b = blockIdx.x / 11;
  const int jc = blockIdx.x % 11;
  const int tid = threadIdx.x;
  const int j = jc * 64 + (tid & 63);
  const int s = tid >> 6;  // 4 c-splits
  __shared__ float hs[DD];
  __shared__ float part[256];

  if (tid < DD) hs[tid] = h_buf[b * DD + tid];
  __syncthreads();

  float a = 0.0f;
  if (j < 672) {
#pragma unroll 8
    for (int cc = 0; cc < 32; ++cc) {
      const int c = s * 32 + cc;
      a += hs[c] * getv<T>(W2, c * 672 + j);
    }
  }
  part[tid] = a;
  __syncthreads();

  if (tid < 64 && j < 672) {
    float r = part[tid] + part[tid + 64] + part[tid + 128] + part[tid + 192] +
              getv<T>(b2, j);
    if (sizeof(T) == 2)
      ((__hip_bfloat16*)out)[b * 672 + j] = __float2bfloat16(r);
    else
      ((float*)out)[b * 672 + j] = r;
  }
}

__global__ __launch_bounds__(256) void k3b_kern(
    const float* h_buf, const void* W2, const void* b2, const int* flag,
    void* out) {
  if (*flag)
    k3b_body<__hip_bfloat16>(h_buf, W2, b2, out);
  else
    k3b_body<float>(h_buf, W2, b2, out);
}

// ---------------------------------------------------------------------------
extern "C" void kernel_launch(void* const* d_in, const int* in_sizes, int n_in,
                              void* d_out, int out_size, void* d_ws,
                              size_t ws_size, hipStream_t stream) {
  const void* x   = d_in[0];
  const void* W_b = d_in[1];
  const void* b_b = d_in[2];
  const void* Wk  = d_in[3];
  const void* Wv  = d_in[4];
  const void* Wq  = d_in[5];
  const void* W_m = d_in[6];
  const void* b_m = d_in[7];
  const void* W_f = d_in[8];
  const void* b_f = d_in[9];
  const void* W1  = d_in[10];
  const void* b1  = d_in[11];
  const void* g1  = d_in[12];
  const void* be1 = d_in[13];
  const void* W2  = d_in[14];
  const void* b2  = d_in[15];

  float* w = (float*)d_ws;
  float* kbuf   = w;                    // 262144
  float* vbuf   = w + 262144;           // 262144
  float* scal4  = w + 524288;           // 8192  (theta,eta,alpha,0) per (b,t)
  float* q_last = w + 532480;           // 1024
  float* f_last = w + 533504;           // 1024
  float* m_last = w + 534528;           // 1024
  int*   flag   = (int*)(w + 535552);   // 1
  float* h_buf  = w + 535556;           // 1024

  k0_detect<<<1, 256, 0, stream>>>(x, flag);
  k1_kern<<<BB * TT, 128, 0, stream>>>(x, W_b, b_b, Wk, Wv, Wq, W_m, b_m,
                                       flag, kbuf, vbuf, scal4, q_last,
                                       f_last);
  k2_scan<<<256, 64, 0, stream>>>(kbuf, vbuf, scal4, q_last, m_last);
  k3a_kern<<<BB, 1024, 0, stream>>>(f_last, m_last, W_f, b_f, W1, b1, g1,
                                    be1, flag, h_buf);
  k3b_kern<<<88, 256, 0, stream>>>(h_buf, W2, b2, flag, d_out);
}

// Round 8
// 153.443 us; speedup vs baseline: 1.3910x; 1.0065x over previous
//
#include <hip/hip_runtime.h>
#include <hip/hip_bf16.h>

#define BB 8
#define TT 256
#define DIN 64
#define DD 128

__device__ __forceinline__ float gelu_tanh(float x) {
  float x3 = x * x * x;
  return 0.5f * x * (1.0f + tanhf(0.7978845608028654f * (x + 0.044715f * x3)));
}
__device__ __forceinline__ float sigmoidf(float x) {
  return 1.0f / (1.0f + __expf(-x));
}

template <typename T> __device__ __forceinline__ float getv(const void* p, int i);
template <> __device__ __forceinline__ float getv<float>(const void* p, int i) {
  return ((const float*)p)[i];
}
template <> __device__ __forceinline__ float getv<__hip_bfloat16>(const void* p, int i) {
  return __bfloat162float(((const __hip_bfloat16*)p)[i]);
}

// DPP-based add from a statically-controlled source lane. All-VALU.
// Harness-validated correct in rounds 1/3/4/5/6/7.
template <int CTRL>
__device__ __forceinline__ float dpp_add(float x) {
  int s = __builtin_amdgcn_update_dpp(0, __float_as_int(x), CTRL, 0xF, 0xF, true);
  return x + __int_as_float(s);
}

// Sum across a 16-lane row.
__device__ __forceinline__ float rowsum16(float p) {
  p = dpp_add<0xB1>(p);   // quad_perm [1,0,3,2]  (xor 1)
  p = dpp_add<0x4E>(p);   // quad_perm [2,3,0,1]  (xor 2)
  p = dpp_add<0x124>(p);  // row_ror:4
  p = dpp_add<0x128>(p);  // row_ror:8
  return p;
}

// Async global->LDS, 16B per lane. LDS dest is wave-uniform base + lane*16;
// global src is per-lane. Tracked by vmcnt. (r6-validated)
__device__ __forceinline__ void gload_lds16(const void* g, void* l) {
  __builtin_amdgcn_global_load_lds(
      (const __attribute__((address_space(1))) void*)g,
      (__attribute__((address_space(3))) void*)l, 16, 0, 0);
}

// Per-thread dtype test on one u16 sample (bf16-decode plausibility).
// Same predicate k0 used for 8 passing rounds; bf16 N(0,1) data ~99.9% good,
// fp32 bitstream ~55% -> thresholds are >13 sigma from both. flag semantics
// preserved; now computed block-locally (k0 kernel removed, r8).
__device__ __forceinline__ int dtype_good(const unsigned short* u, int idx) {
  unsigned int bits = ((unsigned int)u[idx]) << 16;
  float f = __uint_as_float(bits);
  float a = fabsf(f);
  return (a == 0.0f || (a > 1e-4f && a < 100.0f)) ? 1 : 0;
}

// ---------------------------------------------------------------------------
// k1: per (b,t) row: f = gelu(x@W_b+b_b); k=f@Wk; v=f@Wv; meta scalars.
// r8: dtype detection folded in (block-local, LDS-combined across 2 waves).
// ---------------------------------------------------------------------------
template <typename T>
__device__ void k1_body(const void* x, const void* W_b, const void* b_b,
                        const void* Wk, const void* Wv, const void* Wq,
                        const void* W_m, const void* b_m,
                        float* kout, float* vout, float* scal4,
                        float* q_last, float* f_last) {
  const int row = blockIdx.x;          // 0..2047
  const int b = row >> 8, t = row & 255;
  const int tid = threadIdx.x;         // 0..127
  __shared__ float xs[DIN];
  __shared__ float fs[DD];
  if (tid < DIN) xs[tid] = getv<T>(x, row * DIN + tid);
  __syncthreads();

  float acc = getv<T>(b_b, tid);
#pragma unroll 8
  for (int d = 0; d < DIN; ++d) acc += xs[d] * getv<T>(W_b, d * DD + tid);
  float f = gelu_tanh(acc);
  fs[tid] = f;
  __syncthreads();

  float ak = 0.0f, av = 0.0f;
#pragma unroll 8
  for (int c = 0; c < DD; ++c) {
    float fc = fs[c];
    ak += fc * getv<T>(Wk, c * DD + tid);
    av += fc * getv<T>(Wv, c * DD + tid);
  }
  kout[row * DD + tid] = ak;
  vout[row * DD + tid] = av;

  if (t == TT - 1) {
    float aq = 0.0f;
#pragma unroll 8
    for (int c = 0; c < DD; ++c) aq += fs[c] * getv<T>(Wq, c * DD + tid);
    q_last[b * DD + tid] = aq;
    f_last[b * DD + tid] = f;
  }
  if (tid < 4) {
    float val = 0.0f;
    if (tid < 3) {
      float a = getv<T>(b_m, tid);
      for (int c = 0; c < DD; ++c) a += fs[c] * getv<T>(W_m, c * 3 + tid);
      float s = sigmoidf(a);
      val = (tid == 0) ? 0.01f * s : ((tid == 1) ? s : 0.1f * s);
    }
    scal4[row * 4 + tid] = val;  // (theta, eta, alpha, 0)
  }
}

__global__ __launch_bounds__(128) void k1_kern(
    const void* x, const void* W_b, const void* b_b, const void* Wk,
    const void* Wv, const void* Wq, const void* W_m, const void* b_m,
    float* kout, float* vout, float* scal4, float* q_last, float* f_last) {
  // ---- block-local dtype detection (replaces k0 kernel; saves a launch) ----
  __shared__ int gcnt[2];
  {
    const int tid = threadIdx.x;
    const unsigned short* u = (const unsigned short*)x;
    int good = 0;
#pragma unroll
    for (int j = 0; j < 16; ++j) good += dtype_good(u, j * 128 + tid);
    float gf = (float)good;
    gf = rowsum16(gf);
    gf += __shfl_xor(gf, 16);
    gf += __shfl_xor(gf, 32);
    if ((tid & 63) == 0) gcnt[tid >> 6] = (int)(gf + 0.5f);
  }
  __syncthreads();
  const bool isbf16 = (gcnt[0] + gcnt[1] >= 1536);
  __syncthreads();  // gcnt re-use safety before body's LDS writes

  if (isbf16)
    k1_body<__hip_bfloat16>(x, W_b, b_b, Wk, Wv, Wq, W_m, b_m, kout, vout,
                            scal4, q_last, f_last);
  else
    k1_body<float>(x, W_b, b_b, Wk, Wv, Wq, W_m, b_m, kout, vout, scal4,
                   q_last, f_last);
}

// ---------------------------------------------------------------------------
// k2: the scan (r6 structure, validated: LDS chunk double-buffer via
// global_load_lds, one manual vmcnt(0) per 32 steps, DPP reduce,
// 256 blocks x 64 threads = 1 wave/CU). Unchanged.
// ---------------------------------------------------------------------------
__global__ __launch_bounds__(64) void k2_scan(
    const float* __restrict__ kbuf, const float* __restrict__ vbuf,
    const float* __restrict__ scal, const float* __restrict__ q_last,
    float* __restrict__ m_last) {
  const int tid = threadIdx.x;         // 0..63
  const int g = tid & 15;
  const int cidx = tid >> 4;           // chain-in-block 0..3
  const int chain = blockIdx.x * 4 + cidx;
  const int b = chain >> 7;
  const int i = chain & 127;
  const int i0 = (blockIdx.x * 4) & 127;  // first chain's column

  __shared__ float kl[2][32 * DD];     // 2 x 16KB k chunks (32 t-rows each)
  __shared__ float vl[TT * 4];         // v[t][c] for this block's 4 chains
  __shared__ float4 scl[TT];           // (theta,eta,alpha,0) per t

  const float* kslice = kbuf + (size_t)b * TT * DD;
  const float* vslice = vbuf + (size_t)b * TT * DD;

  // ---- prologue: preload v (gather) and sc (coalesced) into LDS ----
  for (int idx = tid; idx < TT * 4; idx += 64)
    vl[idx] = vslice[(idx >> 2) * DD + i0 + (idx & 3)];
  const float4* sp4 = (const float4*)scal + b * TT;
  for (int idx = tid; idx < TT; idx += 64) scl[idx] = sp4[idx];

#define K2_GLL(CH, BUF)                                                      \
  {                                                                          \
    const float* gs = kslice + (CH) * 32 * DD + tid * 4;                     \
    _Pragma("unroll") for (int j = 0; j < 16; ++j)                           \
        gload_lds16(gs + j * 256, &kl[BUF][j * 256]);                        \
  }
  K2_GLL(0, 0);

  float4 Ma = {0, 0, 0, 0}, Mb = {0, 0, 0, 0};
  float4 Sa = {0, 0, 0, 0}, Sb = {0, 0, 0, 0};

#define K2_STEP(KA, KB, VV, SC)                                              \
  {                                                                          \
    float p = (Ma.x * KA.x + Ma.y * KA.y) + (Ma.z * KA.z + Ma.w * KA.w) +    \
              (Mb.x * KB.x + Mb.y * KB.y) + (Mb.z * KB.z + Mb.w * KB.w);     \
    p = rowsum16(p);                                                         \
    const float err = p - VV;                                                \
    const float c = SC.x * err;   /* theta * err */                          \
    const float et = SC.y;        /* eta */                                  \
    const float am = 1.0f - SC.z; /* 1 - alpha */                            \
    Sa.x = et * Sa.x - c * KA.x;  Ma.x = am * Ma.x + Sa.x;                   \
    Sa.y = et * Sa.y - c * KA.y;  Ma.y = am * Ma.y + Sa.y;                   \
    Sa.z = et * Sa.z - c * KA.z;  Ma.z = am * Ma.z + Sa.z;                   \
    Sa.w = et * Sa.w - c * KA.w;  Ma.w = am * Ma.w + Sa.w;                   \
    Sb.x = et * Sb.x - c * KB.x;  Mb.x = am * Mb.x + Sb.x;                   \
    Sb.y = et * Sb.y - c * KB.y;  Mb.y = am * Mb.y + Sb.y;                   \
    Sb.z = et * Sb.z - c * KB.z;  Mb.z = am * Mb.z + Sb.z;                   \
    Sb.w = et * Sb.w - c * KB.w;  Mb.w = am * Mb.w + Sb.w;                   \
  }

  for (int ch = 0; ch < 8; ++ch) {
    asm volatile("s_waitcnt vmcnt(0) lgkmcnt(0)" ::: "memory");
    if (ch < 7) K2_GLL(ch + 1, (ch + 1) & 1);  // next chunk: ~6000cyc cover

    const float* kc = &kl[ch & 1][0];
    const int tbase = ch * 32;

    float4 ka = *(const float4*)(kc + g * 8);
    float4 kb = *(const float4*)(kc + g * 8 + 4);
    float vv = vl[tbase * 4 + cidx];
    float4 sc = scl[tbase];

#pragma unroll
    for (int tt = 0; tt < 32; ++tt) {
      float4 nka, nkb, nsc;
      float nv;
      if (tt < 31) {  // 1-ahead LDS prefetch (within chunk)
        nka = *(const float4*)(kc + (tt + 1) * DD + g * 8);
        nkb = *(const float4*)(kc + (tt + 1) * DD + g * 8 + 4);
        nv = vl[(tbase + tt + 1) * 4 + cidx];
        nsc = scl[tbase + tt + 1];
      }
      K2_STEP(ka, kb, vv, sc);
      if (tt < 31) { ka = nka; kb = nkb; vv = nv; sc = nsc; }
    }
  }
#undef K2_STEP
#undef K2_GLL

  const float4* qp = (const float4*)(q_last + b * DD) + (g << 1);
  float4 qa = qp[0], qb = qp[1];
  float p = (Ma.x * qa.x + Ma.y * qa.y) + (Ma.z * qa.z + Ma.w * qa.w) +
            (Mb.x * qb.x + Mb.y * qb.y) + (Mb.z * qb.z + Mb.w * qb.w);
  p = rowsum16(p);
  if (g == 0) m_last[b * DD + i] = p;
}

// ---------------------------------------------------------------------------
// k3: fused head. 88 blocks (8 b x 11 j-chunks) x 256 threads.
// r8: k3a+k3b fused; each block redundantly computes h for its b (11x, but
// W_f/W1 are L2-hot across 88 blocks and chains are c-split), then its own
// disjoint W2 j-chunk. Saves a launch+gap and the h_buf round-trip.
// Redundant h is bit-identical across the 11 blocks of one b.
// ---------------------------------------------------------------------------
template <typename T>
__device__ void k3_body(const float* f_last, const float* m_last,
                        const void* W_f, const void* b_f, const void* W1,
                        const void* b1, const void* g1, const void* be1,
                        const void* W2, const void* b2, void* out) {
  const int b = blockIdx.x / 11;
  const int jc = blockIdx.x % 11;
  const int tid = threadIdx.x;        // 0..255
  const int o = tid & 127, s = tid >> 7;  // 2 c-splits for h gemvs
  __shared__ float fm[2 * DD];
  __shared__ float part[256];
  __shared__ float fused[DD];
  __shared__ float tmp[DD];
  __shared__ float h[DD];
  __shared__ float smu, srs;

  fm[tid] = (tid < DD) ? f_last[b * DD + tid] : m_last[b * DD + tid - DD];
  __syncthreads();

  // gate gemv: 256 c's, 2 splits x 128
  {
    float a = 0.0f;
#pragma unroll 8
    for (int cc = 0; cc < 128; ++cc) {
      const int c = s * 128 + cc;
      a += fm[c] * getv<T>(W_f, c * DD + o);
    }
    part[tid] = a;
  }
  __syncthreads();
  if (tid < DD) {
    float a = getv<T>(b_f, tid) + part[tid] + part[DD + tid];
    float gte = sigmoidf(a);
    fused[tid] = fm[tid] * gte + fm[DD + tid] * (1.0f - gte);
  }
  __syncthreads();

  // W1 gemv: 128 c's, 2 splits x 64
  {
    float a = 0.0f;
#pragma unroll 8
    for (int cc = 0; cc < 64; ++cc) {
      const int c = s * 64 + cc;
      a += fused[c] * getv<T>(W1, c * DD + o);
    }
    part[tid] = a;
  }
  __syncthreads();
  if (tid < DD) tmp[tid] = getv<T>(b1, tid) + part[tid] + part[DD + tid];
  __syncthreads();

  // LN stats: wave-parallel reduce over 128 elems (first wave only)
  if (tid < 64) {
    float x0 = tmp[tid], x1 = tmp[tid + 64];
    float sm = x0 + x1;
    float sq = x0 * x0 + x1 * x1;
    sm = rowsum16(sm);
    sq = rowsum16(sq);
    sm += __shfl_xor(sm, 16); sq += __shfl_xor(sq, 16);
    sm += __shfl_xor(sm, 32); sq += __shfl_xor(sq, 32);
    if (tid == 0) {
      float mu = sm / (float)DD;
      smu = mu;
      srs = rsqrtf(sq / (float)DD - mu * mu + 1e-5f);
    }
  }
  __syncthreads();

  if (tid < DD)
    h[tid] = gelu_tanh((tmp[tid] - smu) * srs * getv<T>(g1, tid) +
                       getv<T>(be1, tid));
  __syncthreads();

  // W2 chunk: 64 j's x 4 c-splits of 32
  const int j = jc * 64 + (tid & 63);
  const int s2 = tid >> 6;
  float a = 0.0f;
  if (j < 672) {
#pragma unroll 8
    for (int cc = 0; cc < 32; ++cc) {
      const int c = s2 * 32 + cc;
      a += h[c] * getv<T>(W2, c * 672 + j);
    }
  }
  part[tid] = a;
  __syncthreads();

  if (tid < 64 && j < 672) {
    float r = part[tid] + part[tid + 64] + part[tid + 128] + part[tid + 192] +
              getv<T>(b2, j);
    if (sizeof(T) == 2)
      ((__hip_bfloat16*)out)[b * 672 + j] = __float2bfloat16(r);
    else
      ((float*)out)[b * 672 + j] = r;
  }
}

__global__ __launch_bounds__(256) void k3_kern(
    const void* x, const float* f_last, const float* m_last, const void* W_f,
    const void* b_f, const void* W1, const void* b1, const void* g1,
    const void* be1, const void* W2, const void* b2, void* out) {
  // ---- block-local dtype detection (4 waves, LDS-combined) ----
  __shared__ int gcnt[4];
  {
    const int tid = threadIdx.x;
    const unsigned short* u = (const unsigned short*)x;
    int good = 0;
#pragma unroll
    for (int j = 0; j < 8; ++j) good += dtype_good(u, j * 256 + tid);
    float gf = (float)good;
    gf = rowsum16(gf);
    gf += __shfl_xor(gf, 16);
    gf += __shfl_xor(gf, 32);
    if ((tid & 63) == 0) gcnt[tid >> 6] = (int)(gf + 0.5f);
  }
  __syncthreads();
  const bool isbf16 = (gcnt[0] + gcnt[1] + gcnt[2] + gcnt[3] >= 1536);
  __syncthreads();

  if (isbf16)
    k3_body<__hip_bfloat16>(f_last, m_last, W_f, b_f, W1, b1, g1, be1, W2, b2,
                            out);
  else
    k3_body<float>(f_last, m_last, W_f, b_f, W1, b1, g1, be1, W2, b2, out);
}

// ---------------------------------------------------------------------------
extern "C" void kernel_launch(void* const* d_in, const int* in_sizes, int n_in,
                              void* d_out, int out_size, void* d_ws,
                              size_t ws_size, hipStream_t stream) {
  const void* x   = d_in[0];
  const void* W_b = d_in[1];
  const void* b_b = d_in[2];
  const void* Wk  = d_in[3];
  const void* Wv  = d_in[4];
  const void* Wq  = d_in[5];
  const void* W_m = d_in[6];
  const void* b_m = d_in[7];
  const void* W_f = d_in[8];
  const void* b_f = d_in[9];
  const void* W1  = d_in[10];
  const void* b1  = d_in[11];
  const void* g1  = d_in[12];
  const void* be1 = d_in[13];
  const void* W2  = d_in[14];
  const void* b2  = d_in[15];

  float* w = (float*)d_ws;
  float* kbuf   = w;                    // 262144
  float* vbuf   = w + 262144;           // 262144
  float* scal4  = w + 524288;           // 8192  (theta,eta,alpha,0) per (b,t)
  float* q_last = w + 532480;           // 1024
  float* f_last = w + 533504;           // 1024
  float* m_last = w + 534528;           // 1024

  k1_kern<<<BB * TT, 128, 0, stream>>>(x, W_b, b_b, Wk, Wv, Wq, W_m, b_m,
                                       kbuf, vbuf, scal4, q_last, f_last);
  k2_scan<<<256, 64, 0, stream>>>(kbuf, vbuf, scal4, q_last, m_last);
  k3_kern<<<88, 256, 0, stream>>>(x, f_last, m_last, W_f, b_f, W1, b1, g1,
                                  be1, W2, b2, d_out);
}

// Round 9
// 148.459 us; speedup vs baseline: 1.4377x; 1.0336x over previous
//
#include <hip/hip_runtime.h>
#include <hip/hip_bf16.h>

#define BB 8
#define TT 256
#define DIN 64
#define DD 128

__device__ __forceinline__ float gelu_tanh(float x) {
  float x3 = x * x * x;
  return 0.5f * x * (1.0f + tanhf(0.7978845608028654f * (x + 0.044715f * x3)));
}
__device__ __forceinline__ float sigmoidf(float x) {
  return 1.0f / (1.0f + __expf(-x));
}

template <typename T> __device__ __forceinline__ float getv(const void* p, int i);
template <> __device__ __forceinline__ float getv<float>(const void* p, int i) {
  return ((const float*)p)[i];
}
template <> __device__ __forceinline__ float getv<__hip_bfloat16>(const void* p, int i) {
  return __bfloat162float(((const __hip_bfloat16*)p)[i]);
}

// 16B weight chunk -> VEC fma's. VEC=8 (bf16) / 4 (fp32).
template <typename T>
__device__ __forceinline__ void fmaV(float* acc, uint4 wv, float fc);
template <>
__device__ __forceinline__ void fmaV<float>(float* acc, uint4 wv, float fc) {
  acc[0] += fc * __uint_as_float(wv.x);
  acc[1] += fc * __uint_as_float(wv.y);
  acc[2] += fc * __uint_as_float(wv.z);
  acc[3] += fc * __uint_as_float(wv.w);
}
template <>
__device__ __forceinline__ void fmaV<__hip_bfloat16>(float* acc, uint4 wv,
                                                     float fc) {
  const unsigned int u0 = wv.x, u1 = wv.y, u2 = wv.z, u3 = wv.w;
  acc[0] += fc * __uint_as_float(u0 << 16);
  acc[1] += fc * __uint_as_float(u0 & 0xffff0000u);
  acc[2] += fc * __uint_as_float(u1 << 16);
  acc[3] += fc * __uint_as_float(u1 & 0xffff0000u);
  acc[4] += fc * __uint_as_float(u2 << 16);
  acc[5] += fc * __uint_as_float(u2 & 0xffff0000u);
  acc[6] += fc * __uint_as_float(u3 << 16);
  acc[7] += fc * __uint_as_float(u3 & 0xffff0000u);
}

// DPP-based add from a statically-controlled source lane. All-VALU.
// Harness-validated correct in rounds 1/3/4/5/6/7/8.
template <int CTRL>
__device__ __forceinline__ float dpp_add(float x) {
  int s = __builtin_amdgcn_update_dpp(0, __float_as_int(x), CTRL, 0xF, 0xF, true);
  return x + __int_as_float(s);
}

// Sum across a 16-lane row.
__device__ __forceinline__ float rowsum16(float p) {
  p = dpp_add<0xB1>(p);   // quad_perm [1,0,3,2]  (xor 1)
  p = dpp_add<0x4E>(p);   // quad_perm [2,3,0,1]  (xor 2)
  p = dpp_add<0x124>(p);  // row_ror:4
  p = dpp_add<0x128>(p);  // row_ror:8
  return p;
}

// Async global->LDS, 16B per lane. (r6-validated)
__device__ __forceinline__ void gload_lds16(const void* g, void* l) {
  __builtin_amdgcn_global_load_lds(
      (const __attribute__((address_space(1))) void*)g,
      (__attribute__((address_space(3))) void*)l, 16, 0, 0);
}

// Per-thread dtype test on one u16 sample (bf16-decode plausibility).
// bf16 N(0,1) ~99.9% good, fp32 bitstream ~55% -> >13 sigma separation.
__device__ __forceinline__ int dtype_good(const unsigned short* u, int idx) {
  unsigned int bits = ((unsigned int)u[idx]) << 16;
  float f = __uint_as_float(bits);
  float a = fabsf(f);
  return (a == 0.0f || (a > 1e-4f && a < 100.0f)) ? 1 : 0;
}

// ---------------------------------------------------------------------------
// k1: per (b,t) row: f = gelu(x@W_b+b_b); k=f@Wk; v=f@Wv; meta scalars.
// r9: vectorized gemvs. Old: 1 out/thread, ~320 SCALAR (2B/lane) weight
// loads/thread (Common-mistake #2). New: thread (oc,s) loads uint4 = 16B
// (8 bf16 / 4 fp32 weights) per row, accumulates VEC partial outputs over
// its c-split, LDS-combine across splits. Loads/thread 320 -> ~40.
// W_m's 4-thread x 128-iter serial dot -> wave-parallel DPP reduce.
// ---------------------------------------------------------------------------
template <typename T>
__device__ void k1_body(const void* x, const void* W_b, const void* b_b,
                        const void* Wk, const void* Wv, const void* Wq,
                        const void* W_m, const void* b_m,
                        float* kout, float* vout, float* scal4,
                        float* q_last, float* f_last) {
  constexpr int VEC = (sizeof(T) == 2) ? 8 : 4;  // weights per 16B
  constexpr int OC = DD / VEC;                   // o-chunks: 16 / 32
  constexpr int SPL = 128 / OC;                  // c-splits: 8 / 4
  const int row = blockIdx.x;          // 0..2047
  const int b = row >> 8, t = row & 255;
  const int tid = threadIdx.x;         // 0..127
  const int oc = tid % OC, s = tid / OC;

  __shared__ float xs[DIN];
  __shared__ float fs[DD];
  __shared__ float partA[128 * DD / 16];  // SPL*DD <= 1024 floats
  __shared__ float partB[128 * DD / 16];

  if (tid < DIN) xs[tid] = getv<T>(x, row * DIN + tid);
  __syncthreads();

  float acc[VEC];

#define GEMV_PART(Wp, SRC, R, PART)                                          \
  {                                                                          \
    _Pragma("unroll") for (int j = 0; j < VEC; ++j) acc[j] = 0.0f;           \
    constexpr int rps = (R) / SPL;                                           \
    _Pragma("unroll 4") for (int cc = 0; cc < rps; ++cc) {                   \
      const int c = s * rps + cc;                                            \
      const uint4 wv =                                                       \
          *(const uint4*)((const T*)(Wp) + (size_t)c * DD + oc * VEC);       \
      fmaV<T>(acc, wv, (SRC)[c]);                                            \
    }                                                                        \
    _Pragma("unroll") for (int j = 0; j < VEC; ++j)                          \
        (PART)[s * DD + oc * VEC + j] = acc[j];                              \
  }

  // f = gelu(x @ W_b + b_b)
  GEMV_PART(W_b, xs, DIN, partA);
  __syncthreads();
  if (tid < DD) {
    float a = getv<T>(b_b, tid);
#pragma unroll
    for (int ss = 0; ss < SPL; ++ss) a += partA[ss * DD + tid];
    fs[tid] = gelu_tanh(a);
  }
  __syncthreads();

  // k = f @ Wk ; v = f @ Wv  (independent part buffers, one sync)
  GEMV_PART(Wk, fs, DD, partA);
  GEMV_PART(Wv, fs, DD, partB);
  __syncthreads();
  if (tid < DD) {
    float ak = 0.0f, av = 0.0f;
#pragma unroll
    for (int ss = 0; ss < SPL; ++ss) {
      ak += partA[ss * DD + tid];
      av += partB[ss * DD + tid];
    }
    kout[row * DD + tid] = ak;
    vout[row * DD + tid] = av;
  }

  // meta = sigmoid(f @ W_m + b_m): wave-parallel (wave 0), reads fs only
  if (tid < 64) {
    float a3[3];
#pragma unroll
    for (int j = 0; j < 3; ++j) {
      float pj = fs[tid] * getv<T>(W_m, tid * 3 + j) +
                 fs[tid + 64] * getv<T>(W_m, (tid + 64) * 3 + j);
      pj = rowsum16(pj);
      pj += __shfl_xor(pj, 16);
      pj += __shfl_xor(pj, 32);
      a3[j] = pj;
    }
    if (tid == 0) {
      scal4[row * 4 + 0] = 0.01f * sigmoidf(a3[0] + getv<T>(b_m, 0));
      scal4[row * 4 + 1] = sigmoidf(a3[1] + getv<T>(b_m, 1));
      scal4[row * 4 + 2] = 0.1f * sigmoidf(a3[2] + getv<T>(b_m, 2));
      scal4[row * 4 + 3] = 0.0f;
    }
  }

  // q & f kept only for t = T-1 (block-uniform branch -> syncthreads safe)
  if (t == TT - 1) {
    __syncthreads();
    GEMV_PART(Wq, fs, DD, partA);
    __syncthreads();
    if (tid < DD) {
      float aq = 0.0f;
#pragma unroll
      for (int ss = 0; ss < SPL; ++ss) aq += partA[ss * DD + tid];
      q_last[b * DD + tid] = aq;
      f_last[b * DD + tid] = fs[tid];
    }
  }
#undef GEMV_PART
}

__global__ __launch_bounds__(128) void k1_kern(
    const void* x, const void* W_b, const void* b_b, const void* Wk,
    const void* Wv, const void* Wq, const void* W_m, const void* b_m,
    float* kout, float* vout, float* scal4, float* q_last, float* f_last) {
  // ---- block-local dtype detection (r8-validated) ----
  __shared__ int gcnt[2];
  {
    const int tid = threadIdx.x;
    const unsigned short* u = (const unsigned short*)x;
    int good = 0;
#pragma unroll
    for (int j = 0; j < 16; ++j) good += dtype_good(u, j * 128 + tid);
    float gf = (float)good;
    gf = rowsum16(gf);
    gf += __shfl_xor(gf, 16);
    gf += __shfl_xor(gf, 32);
    if ((tid & 63) == 0) gcnt[tid >> 6] = (int)(gf + 0.5f);
  }
  __syncthreads();
  const bool isbf16 = (gcnt[0] + gcnt[1] >= 1536);
  __syncthreads();  // gcnt re-use safety before body's LDS writes

  if (isbf16)
    k1_body<__hip_bfloat16>(x, W_b, b_b, Wk, Wv, Wq, W_m, b_m, kout, vout,
                            scal4, q_last, f_last);
  else
    k1_body<float>(x, W_b, b_b, Wk, Wv, Wq, W_m, b_m, kout, vout, scal4,
                   q_last, f_last);
}

// ---------------------------------------------------------------------------
// k2: the scan (r6 structure, validated; unchanged from r8).
// ---------------------------------------------------------------------------
__global__ __launch_bounds__(64) void k2_scan(
    const float* __restrict__ kbuf, const float* __restrict__ vbuf,
    const float* __restrict__ scal, const float* __restrict__ q_last,
    float* __restrict__ m_last) {
  const int tid = threadIdx.x;         // 0..63
  const int g = tid & 15;
  const int cidx = tid >> 4;           // chain-in-block 0..3
  const int chain = blockIdx.x * 4 + cidx;
  const int b = chain >> 7;
  const int i = chain & 127;
  const int i0 = (blockIdx.x * 4) & 127;  // first chain's column

  __shared__ float kl[2][32 * DD];     // 2 x 16KB k chunks (32 t-rows each)
  __shared__ float vl[TT * 4];         // v[t][c] for this block's 4 chains
  __shared__ float4 scl[TT];           // (theta,eta,alpha,0) per t

  const float* kslice = kbuf + (size_t)b * TT * DD;
  const float* vslice = vbuf + (size_t)b * TT * DD;

  for (int idx = tid; idx < TT * 4; idx += 64)
    vl[idx] = vslice[(idx >> 2) * DD + i0 + (idx & 3)];
  const float4* sp4 = (const float4*)scal + b * TT;
  for (int idx = tid; idx < TT; idx += 64) scl[idx] = sp4[idx];

#define K2_GLL(CH, BUF)                                                      \
  {                                                                          \
    const float* gs = kslice + (CH) * 32 * DD + tid * 4;                     \
    _Pragma("unroll") for (int j = 0; j < 16; ++j)                           \
        gload_lds16(gs + j * 256, &kl[BUF][j * 256]);                        \
  }
  K2_GLL(0, 0);

  float4 Ma = {0, 0, 0, 0}, Mb = {0, 0, 0, 0};
  float4 Sa = {0, 0, 0, 0}, Sb = {0, 0, 0, 0};

#define K2_STEP(KA, KB, VV, SC)                                              \
  {                                                                          \
    float p = (Ma.x * KA.x + Ma.y * KA.y) + (Ma.z * KA.z + Ma.w * KA.w) +    \
              (Mb.x * KB.x + Mb.y * KB.y) + (Mb.z * KB.z + Mb.w * KB.w);     \
    p = rowsum16(p);                                                         \
    const float err = p - VV;                                                \
    const float c = SC.x * err;   /* theta * err */                          \
    const float et = SC.y;        /* eta */                                  \
    const float am = 1.0f - SC.z; /* 1 - alpha */                            \
    Sa.x = et * Sa.x - c * KA.x;  Ma.x = am * Ma.x + Sa.x;                   \
    Sa.y = et * Sa.y - c * KA.y;  Ma.y = am * Ma.y + Sa.y;                   \
    Sa.z = et * Sa.z - c * KA.z;  Ma.z = am * Ma.z + Sa.z;                   \
    Sa.w = et * Sa.w - c * KA.w;  Ma.w = am * Ma.w + Sa.w;                   \
    Sb.x = et * Sb.x - c * KB.x;  Mb.x = am * Mb.x + Sb.x;                   \
    Sb.y = et * Sb.y - c * KB.y;  Mb.y = am * Mb.y + Sb.y;                   \
    Sb.z = et * Sb.z - c * KB.z;  Mb.z = am * Mb.z + Sb.z;                   \
    Sb.w = et * Sb.w - c * KB.w;  Mb.w = am * Mb.w + Sb.w;                   \
  }

  for (int ch = 0; ch < 8; ++ch) {
    asm volatile("s_waitcnt vmcnt(0) lgkmcnt(0)" ::: "memory");
    if (ch < 7) K2_GLL(ch + 1, (ch + 1) & 1);

    const float* kc = &kl[ch & 1][0];
    const int tbase = ch * 32;

    float4 ka = *(const float4*)(kc + g * 8);
    float4 kb = *(const float4*)(kc + g * 8 + 4);
    float vv = vl[tbase * 4 + cidx];
    float4 sc = scl[tbase];

#pragma unroll
    for (int tt = 0; tt < 32; ++tt) {
      float4 nka, nkb, nsc;
      float nv;
      if (tt < 31) {
        nka = *(const float4*)(kc + (tt + 1) * DD + g * 8);
        nkb = *(const float4*)(kc + (tt + 1) * DD + g * 8 + 4);
        nv = vl[(tbase + tt + 1) * 4 + cidx];
        nsc = scl[tbase + tt + 1];
      }
      K2_STEP(ka, kb, vv, sc);
      if (tt < 31) { ka = nka; kb = nkb; vv = nv; sc = nsc; }
    }
  }
#undef K2_STEP
#undef K2_GLL

  const float4* qp = (const float4*)(q_last + b * DD) + (g << 1);
  float4 qa = qp[0], qb = qp[1];
  float p = (Ma.x * qa.x + Ma.y * qa.y) + (Ma.z * qa.z + Ma.w * qa.w) +
            (Mb.x * qb.x + Mb.y * qb.y) + (Mb.z * qb.z + Mb.w * qb.w);
  p = rowsum16(p);
  if (g == 0) m_last[b * DD + i] = p;
}

// ---------------------------------------------------------------------------
// k3: fused head (r8 structure, validated; unchanged).
// 88 blocks (8 b x 11 j-chunks) x 256 threads.
// ---------------------------------------------------------------------------
template <typename T>
__device__ void k3_body(const float* f_last, const float* m_last,
                        const void* W_f, const void* b_f, const void* W1,
                        const void* b1, const void* g1, const void* be1,
                        const void* W2, const void* b2, void* out) {
  const int b = blockIdx.x / 11;
  const int jc = blockIdx.x % 11;
  const int tid = threadIdx.x;        // 0..255
  const int o = tid & 127, s = tid >> 7;  // 2 c-splits for h gemvs
  __shared__ float fm[2 * DD];
  __shared__ float part[256];
  __shared__ float fused[DD];
  __shared__ float tmp[DD];
  __shared__ float h[DD];
  __shared__ float smu, srs;

  fm[tid] = (tid < DD) ? f_last[b * DD + tid] : m_last[b * DD + tid - DD];
  __syncthreads();

  {
    float a = 0.0f;
#pragma unroll 8
    for (int cc = 0; cc < 128; ++cc) {
      const int c = s * 128 + cc;
      a += fm[c] * getv<T>(W_f, c * DD + o);
    }
    part[tid] = a;
  }
  __syncthreads();
  if (tid < DD) {
    float a = getv<T>(b_f, tid) + part[tid] + part[DD + tid];
    float gte = sigmoidf(a);
    fused[tid] = fm[tid] * gte + fm[DD + tid] * (1.0f - gte);
  }
  __syncthreads();

  {
    float a = 0.0f;
#pragma unroll 8
    for (int cc = 0; cc < 64; ++cc) {
      const int c = s * 64 + cc;
      a += fused[c] * getv<T>(W1, c * DD + o);
    }
    part[tid] = a;
  }
  __syncthreads();
  if (tid < DD) tmp[tid] = getv<T>(b1, tid) + part[tid] + part[DD + tid];
  __syncthreads();

  if (tid < 64) {
    float x0 = tmp[tid], x1 = tmp[tid + 64];
    float sm = x0 + x1;
    float sq = x0 * x0 + x1 * x1;
    sm = rowsum16(sm);
    sq = rowsum16(sq);
    sm += __shfl_xor(sm, 16); sq += __shfl_xor(sq, 16);
    sm += __shfl_xor(sm, 32); sq += __shfl_xor(sq, 32);
    if (tid == 0) {
      float mu = sm / (float)DD;
      smu = mu;
      srs = rsqrtf(sq / (float)DD - mu * mu + 1e-5f);
    }
  }
  __syncthreads();

  if (tid < DD)
    h[tid] = gelu_tanh((tmp[tid] - smu) * srs * getv<T>(g1, tid) +
                       getv<T>(be1, tid));
  __syncthreads();

  const int j = jc * 64 + (tid & 63);
  const int s2 = tid >> 6;
  float a = 0.0f;
  if (j < 672) {
#pragma unroll 8
    for (int cc = 0; cc < 32; ++cc) {
      const int c = s2 * 32 + cc;
      a += h[c] * getv<T>(W2, c * 672 + j);
    }
  }
  part[tid] = a;
  __syncthreads();

  if (tid < 64 && j < 672) {
    float r = part[tid] + part[tid + 64] + part[tid + 128] + part[tid + 192] +
              getv<T>(b2, j);
    if (sizeof(T) == 2)
      ((__hip_bfloat16*)out)[b * 672 + j] = __float2bfloat16(r);
    else
      ((float*)out)[b * 672 + j] = r;
  }
}

__global__ __launch_bounds__(256) void k3_kern(
    const void* x, const float* f_last, const float* m_last, const void* W_f,
    const void* b_f, const void* W1, const void* b1, const void* g1,
    const void* be1, const void* W2, const void* b2, void* out) {
  __shared__ int gcnt[4];
  {
    const int tid = threadIdx.x;
    const unsigned short* u = (const unsigned short*)x;
    int good = 0;
#pragma unroll
    for (int j = 0; j < 8; ++j) good += dtype_good(u, j * 256 + tid);
    float gf = (float)good;
    gf = rowsum16(gf);
    gf += __shfl_xor(gf, 16);
    gf += __shfl_xor(gf, 32);
    if ((tid & 63) == 0) gcnt[tid >> 6] = (int)(gf + 0.5f);
  }
  __syncthreads();
  const bool isbf16 = (gcnt[0] + gcnt[1] + gcnt[2] + gcnt[3] >= 1536);
  __syncthreads();

  if (isbf16)
    k3_body<__hip_bfloat16>(f_last, m_last, W_f, b_f, W1, b1, g1, be1, W2, b2,
                            out);
  else
    k3_body<float>(f_last, m_last, W_f, b_f, W1, b1, g1, be1, W2, b2, out);
}

// ---------------------------------------------------------------------------
extern "C" void kernel_launch(void* const* d_in, const int* in_sizes, int n_in,
                              void* d_out, int out_size, void* d_ws,
                              size_t ws_size, hipStream_t stream) {
  const void* x   = d_in[0];
  const void* W_b = d_in[1];
  const void* b_b = d_in[2];
  const void* Wk  = d_in[3];
  const void* Wv  = d_in[4];
  const void* Wq  = d_in[5];
  const void* W_m = d_in[6];
  const void* b_m = d_in[7];
  const void* W_f = d_in[8];
  const void* b_f = d_in[9];
  const void* W1  = d_in[10];
  const void* b1  = d_in[11];
  const void* g1  = d_in[12];
  const void* be1 = d_in[13];
  const void* W2  = d_in[14];
  const void* b2  = d_in[15];

  float* w = (float*)d_ws;
  float* kbuf   = w;                    // 262144
  float* vbuf   = w + 262144;           // 262144
  float* scal4  = w + 524288;           // 8192  (theta,eta,alpha,0) per (b,t)
  float* q_last = w + 532480;           // 1024
  float* f_last = w + 533504;           // 1024
  float* m_last = w + 534528;           // 1024

  k1_kern<<<BB * TT, 128, 0, stream>>>(x, W_b, b_b, Wk, Wv, Wq, W_m, b_m,
                                       kbuf, vbuf, scal4, q_last, f_last);
  k2_scan<<<256, 64, 0, stream>>>(kbuf, vbuf, scal4, q_last, m_last);
  k3_kern<<<88, 256, 0, stream>>>(x, f_last, m_last, W_f, b_f, W1, b1, g1,
                                  be1, W2, b2, d_out);
}

// Round 10
// 144.759 us; speedup vs baseline: 1.4744x; 1.0256x over previous
//
#include <hip/hip_runtime.h>
#include <hip/hip_bf16.h>

#define BB 8
#define TT 256
#define DIN 64
#define DD 128

__device__ __forceinline__ float gelu_tanh(float x) {
  float x3 = x * x * x;
  return 0.5f * x * (1.0f + tanhf(0.7978845608028654f * (x + 0.044715f * x3)));
}
__device__ __forceinline__ float sigmoidf(float x) {
  return 1.0f / (1.0f + __expf(-x));
}

template <typename T> __device__ __forceinline__ float getv(const void* p, int i);
template <> __device__ __forceinline__ float getv<float>(const void* p, int i) {
  return ((const float*)p)[i];
}
template <> __device__ __forceinline__ float getv<__hip_bfloat16>(const void* p, int i) {
  return __bfloat162float(((const __hip_bfloat16*)p)[i]);
}

// 16B weight chunk -> VEC fma's. VEC=8 (bf16) / 4 (fp32). (r9-validated)
template <typename T>
__device__ __forceinline__ void fmaV(float* acc, uint4 wv, float fc);
template <>
__device__ __forceinline__ void fmaV<float>(float* acc, uint4 wv, float fc) {
  acc[0] += fc * __uint_as_float(wv.x);
  acc[1] += fc * __uint_as_float(wv.y);
  acc[2] += fc * __uint_as_float(wv.z);
  acc[3] += fc * __uint_as_float(wv.w);
}
template <>
__device__ __forceinline__ void fmaV<__hip_bfloat16>(float* acc, uint4 wv,
                                                     float fc) {
  const unsigned int u0 = wv.x, u1 = wv.y, u2 = wv.z, u3 = wv.w;
  acc[0] += fc * __uint_as_float(u0 << 16);
  acc[1] += fc * __uint_as_float(u0 & 0xffff0000u);
  acc[2] += fc * __uint_as_float(u1 << 16);
  acc[3] += fc * __uint_as_float(u1 & 0xffff0000u);
  acc[4] += fc * __uint_as_float(u2 << 16);
  acc[5] += fc * __uint_as_float(u2 & 0xffff0000u);
  acc[6] += fc * __uint_as_float(u3 << 16);
  acc[7] += fc * __uint_as_float(u3 & 0xffff0000u);
}

// DPP-based add from a statically-controlled source lane. All-VALU.
// Harness-validated correct in rounds 1/3/4/5/6/7/8/9.
template <int CTRL>
__device__ __forceinline__ float dpp_add(float x) {
  int s = __builtin_amdgcn_update_dpp(0, __float_as_int(x), CTRL, 0xF, 0xF, true);
  return x + __int_as_float(s);
}

// Sum across a 16-lane row.
__device__ __forceinline__ float rowsum16(float p) {
  p = dpp_add<0xB1>(p);   // quad_perm [1,0,3,2]  (xor 1)
  p = dpp_add<0x4E>(p);   // quad_perm [2,3,0,1]  (xor 2)
  p = dpp_add<0x124>(p);  // row_ror:4
  p = dpp_add<0x128>(p);  // row_ror:8
  return p;
}

// Async global->LDS, 16B per lane. (r6-validated)
__device__ __forceinline__ void gload_lds16(const void* g, void* l) {
  __builtin_amdgcn_global_load_lds(
      (const __attribute__((address_space(1))) void*)g,
      (__attribute__((address_space(3))) void*)l, 16, 0, 0);
}

// Per-thread dtype test on one u16 sample (bf16-decode plausibility).
// bf16 N(0,1) ~99.9% good, fp32 bitstream ~55% -> >13 sigma separation.
__device__ __forceinline__ int dtype_good(const unsigned short* u, int idx) {
  unsigned int bits = ((unsigned int)u[idx]) << 16;
  float f = __uint_as_float(bits);
  float a = fabsf(f);
  return (a == 0.0f || (a > 1e-4f && a < 100.0f)) ? 1 : 0;
}

// ---------------------------------------------------------------------------
// k1: per (b,t) row: f = gelu(x@W_b+b_b); k=f@Wk; v=f@Wv; meta scalars.
// (r9 vectorized structure, validated; unchanged this round.)
// ---------------------------------------------------------------------------
template <typename T>
__device__ void k1_body(const void* x, const void* W_b, const void* b_b,
                        const void* Wk, const void* Wv, const void* Wq,
                        const void* W_m, const void* b_m,
                        float* kout, float* vout, float* scal4,
                        float* q_last, float* f_last) {
  constexpr int VEC = (sizeof(T) == 2) ? 8 : 4;  // weights per 16B
  constexpr int OC = DD / VEC;                   // o-chunks: 16 / 32
  constexpr int SPL = 128 / OC;                  // c-splits: 8 / 4
  const int row = blockIdx.x;          // 0..2047
  const int b = row >> 8, t = row & 255;
  const int tid = threadIdx.x;         // 0..127
  const int oc = tid % OC, s = tid / OC;

  __shared__ float xs[DIN];
  __shared__ float fs[DD];
  __shared__ float partA[128 * DD / 16];  // SPL*DD <= 1024 floats
  __shared__ float partB[128 * DD / 16];

  if (tid < DIN) xs[tid] = getv<T>(x, row * DIN + tid);
  __syncthreads();

  float acc[VEC];

#define GEMV_PART(Wp, SRC, R, PART)                                          \
  {                                                                          \
    _Pragma("unroll") for (int j = 0; j < VEC; ++j) acc[j] = 0.0f;           \
    constexpr int rps = (R) / SPL;                                           \
    _Pragma("unroll 4") for (int cc = 0; cc < rps; ++cc) {                   \
      const int c = s * rps + cc;                                            \
      const uint4 wv =                                                       \
          *(const uint4*)((const T*)(Wp) + (size_t)c * DD + oc * VEC);       \
      fmaV<T>(acc, wv, (SRC)[c]);                                            \
    }                                                                        \
    _Pragma("unroll") for (int j = 0; j < VEC; ++j)                          \
        (PART)[s * DD + oc * VEC + j] = acc[j];                              \
  }

  // f = gelu(x @ W_b + b_b)
  GEMV_PART(W_b, xs, DIN, partA);
  __syncthreads();
  if (tid < DD) {
    float a = getv<T>(b_b, tid);
#pragma unroll
    for (int ss = 0; ss < SPL; ++ss) a += partA[ss * DD + tid];
    fs[tid] = gelu_tanh(a);
  }
  __syncthreads();

  // k = f @ Wk ; v = f @ Wv  (independent part buffers, one sync)
  GEMV_PART(Wk, fs, DD, partA);
  GEMV_PART(Wv, fs, DD, partB);
  __syncthreads();
  if (tid < DD) {
    float ak = 0.0f, av = 0.0f;
#pragma unroll
    for (int ss = 0; ss < SPL; ++ss) {
      ak += partA[ss * DD + tid];
      av += partB[ss * DD + tid];
    }
    kout[row * DD + tid] = ak;
    vout[row * DD + tid] = av;
  }

  // meta = sigmoid(f @ W_m + b_m): wave-parallel (wave 0), reads fs only
  if (tid < 64) {
    float a3[3];
#pragma unroll
    for (int j = 0; j < 3; ++j) {
      float pj = fs[tid] * getv<T>(W_m, tid * 3 + j) +
                 fs[tid + 64] * getv<T>(W_m, (tid + 64) * 3 + j);
      pj = rowsum16(pj);
      pj += __shfl_xor(pj, 16);
      pj += __shfl_xor(pj, 32);
      a3[j] = pj;
    }
    if (tid == 0) {
      scal4[row * 4 + 0] = 0.01f * sigmoidf(a3[0] + getv<T>(b_m, 0));
      scal4[row * 4 + 1] = sigmoidf(a3[1] + getv<T>(b_m, 1));
      scal4[row * 4 + 2] = 0.1f * sigmoidf(a3[2] + getv<T>(b_m, 2));
      scal4[row * 4 + 3] = 0.0f;
    }
  }

  // q & f kept only for t = T-1 (block-uniform branch -> syncthreads safe)
  if (t == TT - 1) {
    __syncthreads();
    GEMV_PART(Wq, fs, DD, partA);
    __syncthreads();
    if (tid < DD) {
      float aq = 0.0f;
#pragma unroll
      for (int ss = 0; ss < SPL; ++ss) aq += partA[ss * DD + tid];
      q_last[b * DD + tid] = aq;
      f_last[b * DD + tid] = fs[tid];
    }
  }
#undef GEMV_PART
}

__global__ __launch_bounds__(128) void k1_kern(
    const void* x, const void* W_b, const void* b_b, const void* Wk,
    const void* Wv, const void* Wq, const void* W_m, const void* b_m,
    float* kout, float* vout, float* scal4, float* q_last, float* f_last) {
  __shared__ int gcnt[2];
  {
    const int tid = threadIdx.x;
    const unsigned short* u = (const unsigned short*)x;
    int good = 0;
#pragma unroll
    for (int j = 0; j < 16; ++j) good += dtype_good(u, j * 128 + tid);
    float gf = (float)good;
    gf = rowsum16(gf);
    gf += __shfl_xor(gf, 16);
    gf += __shfl_xor(gf, 32);
    if ((tid & 63) == 0) gcnt[tid >> 6] = (int)(gf + 0.5f);
  }
  __syncthreads();
  const bool isbf16 = (gcnt[0] + gcnt[1] >= 1536);
  __syncthreads();  // gcnt re-use safety before body's LDS writes

  if (isbf16)
    k1_body<__hip_bfloat16>(x, W_b, b_b, Wk, Wv, Wq, W_m, b_m, kout, vout,
                            scal4, q_last, f_last);
  else
    k1_body<float>(x, W_b, b_b, Wk, Wv, Wq, W_m, b_m, kout, vout, scal4,
                   q_last, f_last);
}

// ---------------------------------------------------------------------------
// k2: the scan (r6 structure, validated; unchanged).
// ---------------------------------------------------------------------------
__global__ __launch_bounds__(64) void k2_scan(
    const float* __restrict__ kbuf, const float* __restrict__ vbuf,
    const float* __restrict__ scal, const float* __restrict__ q_last,
    float* __restrict__ m_last) {
  const int tid = threadIdx.x;         // 0..63
  const int g = tid & 15;
  const int cidx = tid >> 4;           // chain-in-block 0..3
  const int chain = blockIdx.x * 4 + cidx;
  const int b = chain >> 7;
  const int i = chain & 127;
  const int i0 = (blockIdx.x * 4) & 127;  // first chain's column

  __shared__ float kl[2][32 * DD];     // 2 x 16KB k chunks (32 t-rows each)
  __shared__ float vl[TT * 4];         // v[t][c] for this block's 4 chains
  __shared__ float4 scl[TT];           // (theta,eta,alpha,0) per t

  const float* kslice = kbuf + (size_t)b * TT * DD;
  const float* vslice = vbuf + (size_t)b * TT * DD;

  for (int idx = tid; idx < TT * 4; idx += 64)
    vl[idx] = vslice[(idx >> 2) * DD + i0 + (idx & 3)];
  const float4* sp4 = (const float4*)scal + b * TT;
  for (int idx = tid; idx < TT; idx += 64) scl[idx] = sp4[idx];

#define K2_GLL(CH, BUF)                                                      \
  {                                                                          \
    const float* gs = kslice + (CH) * 32 * DD + tid * 4;                     \
    _Pragma("unroll") for (int j = 0; j < 16; ++j)                           \
        gload_lds16(gs + j * 256, &kl[BUF][j * 256]);                        \
  }
  K2_GLL(0, 0);

  float4 Ma = {0, 0, 0, 0}, Mb = {0, 0, 0, 0};
  float4 Sa = {0, 0, 0, 0}, Sb = {0, 0, 0, 0};

#define K2_STEP(KA, KB, VV, SC)                                              \
  {                                                                          \
    float p = (Ma.x * KA.x + Ma.y * KA.y) + (Ma.z * KA.z + Ma.w * KA.w) +    \
              (Mb.x * KB.x + Mb.y * KB.y) + (Mb.z * KB.z + Mb.w * KB.w);     \
    p = rowsum16(p);                                                         \
    const float err = p - VV;                                                \
    const float c = SC.x * err;   /* theta * err */                          \
    const float et = SC.y;        /* eta */                                  \
    const float am = 1.0f - SC.z; /* 1 - alpha */                            \
    Sa.x = et * Sa.x - c * KA.x;  Ma.x = am * Ma.x + Sa.x;                   \
    Sa.y = et * Sa.y - c * KA.y;  Ma.y = am * Ma.y + Sa.y;                   \
    Sa.z = et * Sa.z - c * KA.z;  Ma.z = am * Ma.z + Sa.z;                   \
    Sa.w = et * Sa.w - c * KA.w;  Ma.w = am * Ma.w + Sa.w;                   \
    Sb.x = et * Sb.x - c * KB.x;  Mb.x = am * Mb.x + Sb.x;                   \
    Sb.y = et * Sb.y - c * KB.y;  Mb.y = am * Mb.y + Sb.y;                   \
    Sb.z = et * Sb.z - c * KB.z;  Mb.z = am * Mb.z + Sb.z;                   \
    Sb.w = et * Sb.w - c * KB.w;  Mb.w = am * Mb.w + Sb.w;                   \
  }

  for (int ch = 0; ch < 8; ++ch) {
    asm volatile("s_waitcnt vmcnt(0) lgkmcnt(0)" ::: "memory");
    if (ch < 7) K2_GLL(ch + 1, (ch + 1) & 1);

    const float* kc = &kl[ch & 1][0];
    const int tbase = ch * 32;

    float4 ka = *(const float4*)(kc + g * 8);
    float4 kb = *(const float4*)(kc + g * 8 + 4);
    float vv = vl[tbase * 4 + cidx];
    float4 sc = scl[tbase];

#pragma unroll
    for (int tt = 0; tt < 32; ++tt) {
      float4 nka, nkb, nsc;
      float nv;
      if (tt < 31) {
        nka = *(const float4*)(kc + (tt + 1) * DD + g * 8);
        nkb = *(const float4*)(kc + (tt + 1) * DD + g * 8 + 4);
        nv = vl[(tbase + tt + 1) * 4 + cidx];
        nsc = scl[tbase + tt + 1];
      }
      K2_STEP(ka, kb, vv, sc);
      if (tt < 31) { ka = nka; kb = nkb; vv = nv; sc = nsc; }
    }
  }
#undef K2_STEP
#undef K2_GLL

  const float4* qp = (const float4*)(q_last + b * DD) + (g << 1);
  float4 qa = qp[0], qb = qp[1];
  float p = (Ma.x * qa.x + Ma.y * qa.y) + (Ma.z * qa.z + Ma.w * qa.w) +
            (Mb.x * qb.x + Mb.y * qb.y) + (Mb.z * qb.z + Mb.w * qb.w);
  p = rowsum16(p);
  if (g == 0) m_last[b * DD + i] = p;
}

// ---------------------------------------------------------------------------
// k3: fused head. 88 blocks (8 b x 11 j-chunks) x 256 threads.
// r10: gemvs VECTORIZED (the r9 k1 trick ported). Old: ~224 scalar 2B
// weight loads/thread. New: uint4 (8 bf16 / 4 fp32 weights) per load;
// gate/W1 split as (oc,s) like k1; W2 tiled as (jv,s2) over the 64-j chunk
// (row stride 672: byte alignment c*1344 + jbase*2, both 16B multiples).
// Loads/thread ~224 -> ~30.
// ---------------------------------------------------------------------------
template <typename T>
__device__ void k3_body(const float* f_last, const float* m_last,
                        const void* W_f, const void* b_f, const void* W1,
                        const void* b1, const void* g1, const void* be1,
                        const void* W2, const void* b2, void* out) {
  constexpr int VEC = (sizeof(T) == 2) ? 8 : 4;  // weights per 16B
  constexpr int OC = DD / VEC;                   // 16 / 32
  constexpr int SPL = 256 / OC;                  // 16 / 8
  const int b = blockIdx.x / 11;
  const int jc = blockIdx.x % 11;
  const int tid = threadIdx.x;        // 0..255
  const int oc = tid % OC, s = tid / OC;

  __shared__ float fm[2 * DD];
  __shared__ float part[2048];        // max(SPL*DD, SPL2*64) floats
  __shared__ float fused[DD];
  __shared__ float tmp[DD];
  __shared__ float h[DD];
  __shared__ float smu, srs;

  if (tid < 2 * DD)
    fm[tid] = (tid < DD) ? f_last[b * DD + tid] : m_last[b * DD + tid - DD];
  __syncthreads();

  float acc[VEC];

  // gate gemv: rows 2*DD=256, split SPL ways
  {
#pragma unroll
    for (int j = 0; j < VEC; ++j) acc[j] = 0.0f;
    constexpr int rps = 256 / SPL;  // 16 / 32
#pragma unroll 4
    for (int cc = 0; cc < rps; ++cc) {
      const int c = s * rps + cc;
      const uint4 wv =
          *(const uint4*)((const T*)W_f + (size_t)c * DD + oc * VEC);
      fmaV<T>(acc, wv, fm[c]);
    }
#pragma unroll
    for (int j = 0; j < VEC; ++j) part[s * DD + oc * VEC + j] = acc[j];
  }
  __syncthreads();
  if (tid < DD) {
    float a = getv<T>(b_f, tid);
#pragma unroll
    for (int ss = 0; ss < SPL; ++ss) a += part[ss * DD + tid];
    float gte = sigmoidf(a);
    fused[tid] = fm[tid] * gte + fm[DD + tid] * (1.0f - gte);
  }
  __syncthreads();

  // W1 gemv: rows DD=128
  {
#pragma unroll
    for (int j = 0; j < VEC; ++j) acc[j] = 0.0f;
    constexpr int rps = DD / SPL;  // 8 / 16
#pragma unroll 4
    for (int cc = 0; cc < rps; ++cc) {
      const int c = s * rps + cc;
      const uint4 wv =
          *(const uint4*)((const T*)W1 + (size_t)c * DD + oc * VEC);
      fmaV<T>(acc, wv, fused[c]);
    }
#pragma unroll
    for (int j = 0; j < VEC; ++j) part[s * DD + oc * VEC + j] = acc[j];
  }
  __syncthreads();
  if (tid < DD) {
    float a = getv<T>(b1, tid);
#pragma unroll
    for (int ss = 0; ss < SPL; ++ss) a += part[ss * DD + tid];
    tmp[tid] = a;
  }
  __syncthreads();

  // LN stats: wave-parallel reduce over 128 elems (first wave only)
  if (tid < 64) {
    float x0 = tmp[tid], x1 = tmp[tid + 64];
    float sm = x0 + x1;
    float sq = x0 * x0 + x1 * x1;
    sm = rowsum16(sm);
    sq = rowsum16(sq);
    sm += __shfl_xor(sm, 16); sq += __shfl_xor(sq, 16);
    sm += __shfl_xor(sm, 32); sq += __shfl_xor(sq, 32);
    if (tid == 0) {
      float mu = sm / (float)DD;
      smu = mu;
      srs = rsqrtf(sq / (float)DD - mu * mu + 1e-5f);
    }
  }
  __syncthreads();

  if (tid < DD)
    h[tid] = gelu_tanh((tmp[tid] - smu) * srs * getv<T>(g1, tid) +
                       getv<T>(be1, tid));
  __syncthreads();

  // W2 chunk gemv: 64 j's tiled as (jv x VEC), c split SPL2 ways
  {
    constexpr int NJ = 64 / VEC;     // 8 / 16
    constexpr int SPL2 = 256 / NJ;   // 32 / 16
    constexpr int rps2 = DD / SPL2;  // 4 / 8
    const int jv = tid % NJ, s2 = tid / NJ;
    const int jbase = jc * 64 + jv * VEC;
#pragma unroll
    for (int j = 0; j < VEC; ++j) acc[j] = 0.0f;
    if (jbase < 672) {  // jc=10 tail guard (uniform per thread)
#pragma unroll
      for (int cc = 0; cc < rps2; ++cc) {
        const int c = s2 * rps2 + cc;
        const uint4 wv = *(const uint4*)((const T*)W2 + (size_t)c * 672 + jbase);
        fmaV<T>(acc, wv, h[c]);
      }
    }
#pragma unroll
    for (int j = 0; j < VEC; ++j) part[s2 * 64 + jv * VEC + j] = acc[j];
    __syncthreads();

    const int j = jc * 64 + tid;
    if (tid < 64 && j < 672) {
      float r = getv<T>(b2, j);
#pragma unroll
      for (int ss = 0; ss < SPL2; ++ss) r += part[ss * 64 + tid];
      if (sizeof(T) == 2)
        ((__hip_bfloat16*)out)[b * 672 + j] = __float2bfloat16(r);
      else
        ((float*)out)[b * 672 + j] = r;
    }
  }
}

__global__ __launch_bounds__(256) void k3_kern(
    const void* x, const float* f_last, const float* m_last, const void* W_f,
    const void* b_f, const void* W1, const void* b1, const void* g1,
    const void* be1, const void* W2, const void* b2, void* out) {
  __shared__ int gcnt[4];
  {
    const int tid = threadIdx.x;
    const unsigned short* u = (const unsigned short*)x;
    int good = 0;
#pragma unroll
    for (int j = 0; j < 8; ++j) good += dtype_good(u, j * 256 + tid);
    float gf = (float)good;
    gf = rowsum16(gf);
    gf += __shfl_xor(gf, 16);
    gf += __shfl_xor(gf, 32);
    if ((tid & 63) == 0) gcnt[tid >> 6] = (int)(gf + 0.5f);
  }
  __syncthreads();
  const bool isbf16 = (gcnt[0] + gcnt[1] + gcnt[2] + gcnt[3] >= 1536);
  __syncthreads();

  if (isbf16)
    k3_body<__hip_bfloat16>(f_last, m_last, W_f, b_f, W1, b1, g1, be1, W2, b2,
                            out);
  else
    k3_body<float>(f_last, m_last, W_f, b_f, W1, b1, g1, be1, W2, b2, out);
}

// ---------------------------------------------------------------------------
extern "C" void kernel_launch(void* const* d_in, const int* in_sizes, int n_in,
                              void* d_out, int out_size, void* d_ws,
                              size_t ws_size, hipStream_t stream) {
  const void* x   = d_in[0];
  const void* W_b = d_in[1];
  const void* b_b = d_in[2];
  const void* Wk  = d_in[3];
  const void* Wv  = d_in[4];
  const void* Wq  = d_in[5];
  const void* W_m = d_in[6];
  const void* b_m = d_in[7];
  const void* W_f = d_in[8];
  const void* b_f = d_in[9];
  const void* W1  = d_in[10];
  const void* b1  = d_in[11];
  const void* g1  = d_in[12];
  const void* be1 = d_in[13];
  const void* W2  = d_in[14];
  const void* b2  = d_in[15];

  float* w = (float*)d_ws;
  float* kbuf   = w;                    // 262144
  float* vbuf   = w + 262144;           // 262144
  float* scal4  = w + 524288;           // 8192  (theta,eta,alpha,0) per (b,t)
  float* q_last = w + 532480;           // 1024
  float* f_last = w + 533504;           // 1024
  float* m_last = w + 534528;           // 1024

  k1_kern<<<BB * TT, 128, 0, stream>>>(x, W_b, b_b, Wk, Wv, Wq, W_m, b_m,
                                       kbuf, vbuf, scal4, q_last, f_last);
  k2_scan<<<256, 64, 0, stream>>>(kbuf, vbuf, scal4, q_last, m_last);
  k3_kern<<<88, 256, 0, stream>>>(x, f_last, m_last, W_f, b_f, W1, b1, g1,
                                  be1, W2, b2, d_out);
}

// Round 11
// 144.718 us; speedup vs baseline: 1.4749x; 1.0003x over previous
//
#include <hip/hip_runtime.h>
#include <hip/hip_bf16.h>

#define BB 8
#define TT 256
#define DIN 64
#define DD 128

__device__ __forceinline__ float gelu_tanh(float x) {
  float x3 = x * x * x;
  return 0.5f * x * (1.0f + tanhf(0.7978845608028654f * (x + 0.044715f * x3)));
}
__device__ __forceinline__ float sigmoidf(float x) {
  return 1.0f / (1.0f + __expf(-x));
}

template <typename T> __device__ __forceinline__ float getv(const void* p, int i);
template <> __device__ __forceinline__ float getv<float>(const void* p, int i) {
  return ((const float*)p)[i];
}
template <> __device__ __forceinline__ float getv<__hip_bfloat16>(const void* p, int i) {
  return __bfloat162float(((const __hip_bfloat16*)p)[i]);
}

// 16B weight chunk -> VEC fma's. VEC=8 (bf16) / 4 (fp32). (r9/r10-validated)
template <typename T>
__device__ __forceinline__ void fmaV(float* acc, uint4 wv, float fc);
template <>
__device__ __forceinline__ void fmaV<float>(float* acc, uint4 wv, float fc) {
  acc[0] += fc * __uint_as_float(wv.x);
  acc[1] += fc * __uint_as_float(wv.y);
  acc[2] += fc * __uint_as_float(wv.z);
  acc[3] += fc * __uint_as_float(wv.w);
}
template <>
__device__ __forceinline__ void fmaV<__hip_bfloat16>(float* acc, uint4 wv,
                                                     float fc) {
  const unsigned int u0 = wv.x, u1 = wv.y, u2 = wv.z, u3 = wv.w;
  acc[0] += fc * __uint_as_float(u0 << 16);
  acc[1] += fc * __uint_as_float(u0 & 0xffff0000u);
  acc[2] += fc * __uint_as_float(u1 << 16);
  acc[3] += fc * __uint_as_float(u1 & 0xffff0000u);
  acc[4] += fc * __uint_as_float(u2 << 16);
  acc[5] += fc * __uint_as_float(u2 & 0xffff0000u);
  acc[6] += fc * __uint_as_float(u3 << 16);
  acc[7] += fc * __uint_as_float(u3 & 0xffff0000u);
}

// DPP-based add from a statically-controlled source lane. All-VALU.
// Harness-validated correct in rounds 1/3/4/5/6/7/8/9/10.
template <int CTRL>
__device__ __forceinline__ float dpp_add(float x) {
  int s = __builtin_amdgcn_update_dpp(0, __float_as_int(x), CTRL, 0xF, 0xF, true);
  return x + __int_as_float(s);
}

// Sum across a 16-lane row.
__device__ __forceinline__ float rowsum16(float p) {
  p = dpp_add<0xB1>(p);   // quad_perm [1,0,3,2]  (xor 1)
  p = dpp_add<0x4E>(p);   // quad_perm [2,3,0,1]  (xor 2)
  p = dpp_add<0x124>(p);  // row_ror:4
  p = dpp_add<0x128>(p);  // row_ror:8
  return p;
}

// Async global->LDS, 16B per lane. (r6-validated)
__device__ __forceinline__ void gload_lds16(const void* g, void* l) {
  __builtin_amdgcn_global_load_lds(
      (const __attribute__((address_space(1))) void*)g,
      (__attribute__((address_space(3))) void*)l, 16, 0, 0);
}

// Per-thread dtype test on one u16 sample (bf16-decode plausibility).
// bf16 N(0,1) ~99.9% good, fp32 bitstream ~55% -> >13 sigma separation.
__device__ __forceinline__ int dtype_good(const unsigned short* u, int idx) {
  unsigned int bits = ((unsigned int)u[idx]) << 16;
  float f = __uint_as_float(bits);
  float a = fabsf(f);
  return (a == 0.0f || (a > 1e-4f && a < 100.0f)) ? 1 : 0;
}

// ---------------------------------------------------------------------------
// k1: per (b,t) row: f = gelu(x@W_b+b_b); k=f@Wk; v=f@Wv; meta scalars.
// (r9 vectorized structure, validated; unchanged.)
// ---------------------------------------------------------------------------
template <typename T>
__device__ void k1_body(const void* x, const void* W_b, const void* b_b,
                        const void* Wk, const void* Wv, const void* Wq,
                        const void* W_m, const void* b_m,
                        float* kout, float* vout, float* scal4,
                        float* q_last, float* f_last) {
  constexpr int VEC = (sizeof(T) == 2) ? 8 : 4;  // weights per 16B
  constexpr int OC = DD / VEC;                   // o-chunks: 16 / 32
  constexpr int SPL = 128 / OC;                  // c-splits: 8 / 4
  const int row = blockIdx.x;          // 0..2047
  const int b = row >> 8, t = row & 255;
  const int tid = threadIdx.x;         // 0..127
  const int oc = tid % OC, s = tid / OC;

  __shared__ float xs[DIN];
  __shared__ float fs[DD];
  __shared__ float partA[128 * DD / 16];  // SPL*DD <= 1024 floats
  __shared__ float partB[128 * DD / 16];

  if (tid < DIN) xs[tid] = getv<T>(x, row * DIN + tid);
  __syncthreads();

  float acc[VEC];

#define GEMV_PART(Wp, SRC, R, PART)                                          \
  {                                                                          \
    _Pragma("unroll") for (int j = 0; j < VEC; ++j) acc[j] = 0.0f;           \
    constexpr int rps = (R) / SPL;                                           \
    _Pragma("unroll 4") for (int cc = 0; cc < rps; ++cc) {                   \
      const int c = s * rps + cc;                                            \
      const uint4 wv =                                                       \
          *(const uint4*)((const T*)(Wp) + (size_t)c * DD + oc * VEC);       \
      fmaV<T>(acc, wv, (SRC)[c]);                                            \
    }                                                                        \
    _Pragma("unroll") for (int j = 0; j < VEC; ++j)                          \
        (PART)[s * DD + oc * VEC + j] = acc[j];                              \
  }

  // f = gelu(x @ W_b + b_b)
  GEMV_PART(W_b, xs, DIN, partA);
  __syncthreads();
  if (tid < DD) {
    float a = getv<T>(b_b, tid);
#pragma unroll
    for (int ss = 0; ss < SPL; ++ss) a += partA[ss * DD + tid];
    fs[tid] = gelu_tanh(a);
  }
  __syncthreads();

  // k = f @ Wk ; v = f @ Wv  (independent part buffers, one sync)
  GEMV_PART(Wk, fs, DD, partA);
  GEMV_PART(Wv, fs, DD, partB);
  __syncthreads();
  if (tid < DD) {
    float ak = 0.0f, av = 0.0f;
#pragma unroll
    for (int ss = 0; ss < SPL; ++ss) {
      ak += partA[ss * DD + tid];
      av += partB[ss * DD + tid];
    }
    kout[row * DD + tid] = ak;
    vout[row * DD + tid] = av;
  }

  // meta = sigmoid(f @ W_m + b_m): wave-parallel (wave 0), reads fs only
  if (tid < 64) {
    float a3[3];
#pragma unroll
    for (int j = 0; j < 3; ++j) {
      float pj = fs[tid] * getv<T>(W_m, tid * 3 + j) +
                 fs[tid + 64] * getv<T>(W_m, (tid + 64) * 3 + j);
      pj = rowsum16(pj);
      pj += __shfl_xor(pj, 16);
      pj += __shfl_xor(pj, 32);
      a3[j] = pj;
    }
    if (tid == 0) {
      scal4[row * 4 + 0] = 0.01f * sigmoidf(a3[0] + getv<T>(b_m, 0));
      scal4[row * 4 + 1] = sigmoidf(a3[1] + getv<T>(b_m, 1));
      scal4[row * 4 + 2] = 0.1f * sigmoidf(a3[2] + getv<T>(b_m, 2));
      scal4[row * 4 + 3] = 0.0f;
    }
  }

  // q & f kept only for t = T-1 (block-uniform branch -> syncthreads safe)
  if (t == TT - 1) {
    __syncthreads();
    GEMV_PART(Wq, fs, DD, partA);
    __syncthreads();
    if (tid < DD) {
      float aq = 0.0f;
#pragma unroll
      for (int ss = 0; ss < SPL; ++ss) aq += partA[ss * DD + tid];
      q_last[b * DD + tid] = aq;
      f_last[b * DD + tid] = fs[tid];
    }
  }
#undef GEMV_PART
}

__global__ __launch_bounds__(128) void k1_kern(
    const void* x, const void* W_b, const void* b_b, const void* Wk,
    const void* Wv, const void* Wq, const void* W_m, const void* b_m,
    float* kout, float* vout, float* scal4, float* q_last, float* f_last) {
  __shared__ int gcnt[2];
  {
    const int tid = threadIdx.x;
    const unsigned short* u = (const unsigned short*)x;
    int good = 0;
#pragma unroll
    for (int j = 0; j < 16; ++j) good += dtype_good(u, j * 128 + tid);
    float gf = (float)good;
    gf = rowsum16(gf);
    gf += __shfl_xor(gf, 16);
    gf += __shfl_xor(gf, 32);
    if ((tid & 63) == 0) gcnt[tid >> 6] = (int)(gf + 0.5f);
  }
  __syncthreads();
  const bool isbf16 = (gcnt[0] + gcnt[1] >= 1536);
  __syncthreads();  // gcnt re-use safety before body's LDS writes

  if (isbf16)
    k1_body<__hip_bfloat16>(x, W_b, b_b, Wk, Wv, Wq, W_m, b_m, kout, vout,
                            scal4, q_last, f_last);
  else
    k1_body<float>(x, W_b, b_b, Wk, Wv, Wq, W_m, b_m, kout, vout, scal4,
                   q_last, f_last);
}

// ---------------------------------------------------------------------------
// k2: the scan (r6 structure + r11 bank-conflict fix).
//
// r11: SQ_LDS_BANK_CONFLICT was 524288/dispatch (8 cyc/step, on the
// dependent ds_read path). Old fragment map: lane g owned k[g*8..g*8+8)
// -> each ds_read_b128 hits banks (g*8)%32 -> lanes {g,g+4,g+8,g+12}
// alias = 4-way conflict (1.58x, m136). New map: lane g owns
// k[g*4..g*4+4) and k[64+g*4..64+g*4+4) -> each read is a contiguous
// 256B span across 16 lanes -> 2-way alias = free (1.02x, m136).
// Math is mapping-invariant: M/S fragments are lane-local against the
// lane's own k/q elems; rowsum16 covers all 16 lanes. Only the k-read
// and q-read offsets change; staging/updates/outputs untouched.
// ---------------------------------------------------------------------------
__global__ __launch_bounds__(64) void k2_scan(
    const float* __restrict__ kbuf, const float* __restrict__ vbuf,
    const float* __restrict__ scal, const float* __restrict__ q_last,
    float* __restrict__ m_last) {
  const int tid = threadIdx.x;         // 0..63
  const int g = tid & 15;
  const int cidx = tid >> 4;           // chain-in-block 0..3
  const int chain = blockIdx.x * 4 + cidx;
  const int b = chain >> 7;
  const int i = chain & 127;
  const int i0 = (blockIdx.x * 4) & 127;  // first chain's column

  __shared__ float kl[2][32 * DD];     // 2 x 16KB k chunks (32 t-rows each)
  __shared__ float vl[TT * 4];         // v[t][c] for this block's 4 chains
  __shared__ float4 scl[TT];           // (theta,eta,alpha,0) per t

  const float* kslice = kbuf + (size_t)b * TT * DD;
  const float* vslice = vbuf + (size_t)b * TT * DD;

  for (int idx = tid; idx < TT * 4; idx += 64)
    vl[idx] = vslice[(idx >> 2) * DD + i0 + (idx & 3)];
  const float4* sp4 = (const float4*)scal + b * TT;
  for (int idx = tid; idx < TT; idx += 64) scl[idx] = sp4[idx];

#define K2_GLL(CH, BUF)                                                      \
  {                                                                          \
    const float* gs = kslice + (CH) * 32 * DD + tid * 4;                     \
    _Pragma("unroll") for (int j = 0; j < 16; ++j)                           \
        gload_lds16(gs + j * 256, &kl[BUF][j * 256]);                        \
  }
  K2_GLL(0, 0);

  float4 Ma = {0, 0, 0, 0}, Mb = {0, 0, 0, 0};
  float4 Sa = {0, 0, 0, 0}, Sb = {0, 0, 0, 0};

#define K2_STEP(KA, KB, VV, SC)                                              \
  {                                                                          \
    float p = (Ma.x * KA.x + Ma.y * KA.y) + (Ma.z * KA.z + Ma.w * KA.w) +    \
              (Mb.x * KB.x + Mb.y * KB.y) + (Mb.z * KB.z + Mb.w * KB.w);     \
    p = rowsum16(p);                                                         \
    const float err = p - VV;                                                \
    const float c = SC.x * err;   /* theta * err */                          \
    const float et = SC.y;        /* eta */                                  \
    const float am = 1.0f - SC.z; /* 1 - alpha */                            \
    Sa.x = et * Sa.x - c * KA.x;  Ma.x = am * Ma.x + Sa.x;                   \
    Sa.y = et * Sa.y - c * KA.y;  Ma.y = am * Ma.y + Sa.y;                   \
    Sa.z = et * Sa.z - c * KA.z;  Ma.z = am * Ma.z + Sa.z;                   \
    Sa.w = et * Sa.w - c * KA.w;  Ma.w = am * Ma.w + Sa.w;                   \
    Sb.x = et * Sb.x - c * KB.x;  Mb.x = am * Mb.x + Sb.x;                   \
    Sb.y = et * Sb.y - c * KB.y;  Mb.y = am * Mb.y + Sb.y;                   \
    Sb.z = et * Sb.z - c * KB.z;  Mb.z = am * Mb.z + Sb.z;                   \
    Sb.w = et * Sb.w - c * KB.w;  Mb.w = am * Mb.w + Sb.w;                   \
  }

  for (int ch = 0; ch < 8; ++ch) {
    asm volatile("s_waitcnt vmcnt(0) lgkmcnt(0)" ::: "memory");
    if (ch < 7) K2_GLL(ch + 1, (ch + 1) & 1);

    const float* kc = &kl[ch & 1][0];
    const int tbase = ch * 32;

    // r11 mapping: lane g owns elems [g*4, g*4+4) and [64+g*4, 64+g*4+4)
    float4 ka = *(const float4*)(kc + g * 4);
    float4 kb = *(const float4*)(kc + 64 + g * 4);
    float vv = vl[tbase * 4 + cidx];
    float4 sc = scl[tbase];

#pragma unroll
    for (int tt = 0; tt < 32; ++tt) {
      float4 nka, nkb, nsc;
      float nv;
      if (tt < 31) {
        nka = *(const float4*)(kc + (tt + 1) * DD + g * 4);
        nkb = *(const float4*)(kc + (tt + 1) * DD + 64 + g * 4);
        nv = vl[(tbase + tt + 1) * 4 + cidx];
        nsc = scl[tbase + tt + 1];
      }
      K2_STEP(ka, kb, vv, sc);
      if (tt < 31) { ka = nka; kb = nkb; vv = nv; sc = nsc; }
    }
  }
#undef K2_STEP
#undef K2_GLL

  // q read must use the same fragment mapping
  const float* qb0 = q_last + b * DD;
  float4 qa = *(const float4*)(qb0 + g * 4);
  float4 qb = *(const float4*)(qb0 + 64 + g * 4);
  float p = (Ma.x * qa.x + Ma.y * qa.y) + (Ma.z * qa.z + Ma.w * qa.w) +
            (Mb.x * qb.x + Mb.y * qb.y) + (Mb.z * qb.z + Mb.w * qb.w);
  p = rowsum16(p);
  if (g == 0) m_last[b * DD + i] = p;
}

// ---------------------------------------------------------------------------
// k3: fused head (r10 vectorized structure, validated; unchanged).
// 88 blocks (8 b x 11 j-chunks) x 256 threads.
// ---------------------------------------------------------------------------
template <typename T>
__device__ void k3_body(const float* f_last, const float* m_last,
                        const void* W_f, const void* b_f, const void* W1,
                        const void* b1, const void* g1, const void* be1,
                        const void* W2, const void* b2, void* out) {
  constexpr int VEC = (sizeof(T) == 2) ? 8 : 4;  // weights per 16B
  constexpr int OC = DD / VEC;                   // 16 / 32
  constexpr int SPL = 256 / OC;                  // 16 / 8
  const int b = blockIdx.x / 11;
  const int jc = blockIdx.x % 11;
  const int tid = threadIdx.x;        // 0..255
  const int oc = tid % OC, s = tid / OC;

  __shared__ float fm[2 * DD];
  __shared__ float part[2048];        // max(SPL*DD, SPL2*64) floats
  __shared__ float fused[DD];
  __shared__ float tmp[DD];
  __shared__ float h[DD];
  __shared__ float smu, srs;

  if (tid < 2 * DD)
    fm[tid] = (tid < DD) ? f_last[b * DD + tid] : m_last[b * DD + tid - DD];
  __syncthreads();

  float acc[VEC];

  // gate gemv: rows 2*DD=256, split SPL ways
  {
#pragma unroll
    for (int j = 0; j < VEC; ++j) acc[j] = 0.0f;
    constexpr int rps = 256 / SPL;  // 16 / 32
#pragma unroll 4
    for (int cc = 0; cc < rps; ++cc) {
      const int c = s * rps + cc;
      const uint4 wv =
          *(const uint4*)((const T*)W_f + (size_t)c * DD + oc * VEC);
      fmaV<T>(acc, wv, fm[c]);
    }
#pragma unroll
    for (int j = 0; j < VEC; ++j) part[s * DD + oc * VEC + j] = acc[j];
  }
  __syncthreads();
  if (tid < DD) {
    float a = getv<T>(b_f, tid);
#pragma unroll
    for (int ss = 0; ss < SPL; ++ss) a += part[ss * DD + tid];
    float gte = sigmoidf(a);
    fused[tid] = fm[tid] * gte + fm[DD + tid] * (1.0f - gte);
  }
  __syncthreads();

  // W1 gemv: rows DD=128
  {
#pragma unroll
    for (int j = 0; j < VEC; ++j) acc[j] = 0.0f;
    constexpr int rps = DD / SPL;  // 8 / 16
#pragma unroll 4
    for (int cc = 0; cc < rps; ++cc) {
      const int c = s * rps + cc;
      const uint4 wv =
          *(const uint4*)((const T*)W1 + (size_t)c * DD + oc * VEC);
      fmaV<T>(acc, wv, fused[c]);
    }
#pragma unroll
    for (int j = 0; j < VEC; ++j) part[s * DD + oc * VEC + j] = acc[j];
  }
  __syncthreads();
  if (tid < DD) {
    float a = getv<T>(b1, tid);
#pragma unroll
    for (int ss = 0; ss < SPL; ++ss) a += part[ss * DD + tid];
    tmp[tid] = a;
  }
  __syncthreads();

  // LN stats: wave-parallel reduce over 128 elems (first wave only)
  if (tid < 64) {
    float x0 = tmp[tid], x1 = tmp[tid + 64];
    float sm = x0 + x1;
    float sq = x0 * x0 + x1 * x1;
    sm = rowsum16(sm);
    sq = rowsum16(sq);
    sm += __shfl_xor(sm, 16); sq += __shfl_xor(sq, 16);
    sm += __shfl_xor(sm, 32); sq += __shfl_xor(sq, 32);
    if (tid == 0) {
      float mu = sm / (float)DD;
      smu = mu;
      srs = rsqrtf(sq / (float)DD - mu * mu + 1e-5f);
    }
  }
  __syncthreads();

  if (tid < DD)
    h[tid] = gelu_tanh((tmp[tid] - smu) * srs * getv<T>(g1, tid) +
                       getv<T>(be1, tid));
  __syncthreads();

  // W2 chunk gemv: 64 j's tiled as (jv x VEC), c split SPL2 ways
  {
    constexpr int NJ = 64 / VEC;     // 8 / 16
    constexpr int SPL2 = 256 / NJ;   // 32 / 16
    constexpr int rps2 = DD / SPL2;  // 4 / 8
    const int jv = tid % NJ, s2 = tid / NJ;
    const int jbase = jc * 64 + jv * VEC;
#pragma unroll
    for (int j = 0; j < VEC; ++j) acc[j] = 0.0f;
    if (jbase < 672) {  // jc=10 tail guard (uniform per thread)
#pragma unroll
      for (int cc = 0; cc < rps2; ++cc) {
        const int c = s2 * rps2 + cc;
        const uint4 wv = *(const uint4*)((const T*)W2 + (size_t)c * 672 + jbase);
        fmaV<T>(acc, wv, h[c]);
      }
    }
#pragma unroll
    for (int j = 0; j < VEC; ++j) part[s2 * 64 + jv * VEC + j] = acc[j];
    __syncthreads();

    const int j = jc * 64 + tid;
    if (tid < 64 && j < 672) {
      float r = getv<T>(b2, j);
#pragma unroll
      for (int ss = 0; ss < SPL2; ++ss) r += part[ss * 64 + tid];
      if (sizeof(T) == 2)
        ((__hip_bfloat16*)out)[b * 672 + j] = __float2bfloat16(r);
      else
        ((float*)out)[b * 672 + j] = r;
    }
  }
}

__global__ __launch_bounds__(256) void k3_kern(
    const void* x, const float* f_last, const float* m_last, const void* W_f,
    const void* b_f, const void* W1, const void* b1, const void* g1,
    const void* be1, const void* W2, const void* b2, void* out) {
  __shared__ int gcnt[4];
  {
    const int tid = threadIdx.x;
    const unsigned short* u = (const unsigned short*)x;
    int good = 0;
#pragma unroll
    for (int j = 0; j < 8; ++j) good += dtype_good(u, j * 256 + tid);
    float gf = (float)good;
    gf = rowsum16(gf);
    gf += __shfl_xor(gf, 16);
    gf += __shfl_xor(gf, 32);
    if ((tid & 63) == 0) gcnt[tid >> 6] = (int)(gf + 0.5f);
  }
  __syncthreads();
  const bool isbf16 = (gcnt[0] + gcnt[1] + gcnt[2] + gcnt[3] >= 1536);
  __syncthreads();

  if (isbf16)
    k3_body<__hip_bfloat16>(f_last, m_last, W_f, b_f, W1, b1, g1, be1, W2, b2,
                            out);
  else
    k3_body<float>(f_last, m_last, W_f, b_f, W1, b1, g1, be1, W2, b2, out);
}

// ---------------------------------------------------------------------------
extern "C" void kernel_launch(void* const* d_in, const int* in_sizes, int n_in,
                              void* d_out, int out_size, void* d_ws,
                              size_t ws_size, hipStream_t stream) {
  const void* x   = d_in[0];
  const void* W_b = d_in[1];
  const void* b_b = d_in[2];
  const void* Wk  = d_in[3];
  const void* Wv  = d_in[4];
  const void* Wq  = d_in[5];
  const void* W_m = d_in[6];
  const void* b_m = d_in[7];
  const void* W_f = d_in[8];
  const void* b_f = d_in[9];
  const void* W1  = d_in[10];
  const void* b1  = d_in[11];
  const void* g1  = d_in[12];
  const void* be1 = d_in[13];
  const void* W2  = d_in[14];
  const void* b2  = d_in[15];

  float* w = (float*)d_ws;
  float* kbuf   = w;                    // 262144
  float* vbuf   = w + 262144;           // 262144
  float* scal4  = w + 524288;           // 8192  (theta,eta,alpha,0) per (b,t)
  float* q_last = w + 532480;           // 1024
  float* f_last = w + 533504;           // 1024
  float* m_last = w + 534528;           // 1024

  k1_kern<<<BB * TT, 128, 0, stream>>>(x, W_b, b_b, Wk, Wv, Wq, W_m, b_m,
                                       kbuf, vbuf, scal4, q_last, f_last);
  k2_scan<<<256, 64, 0, stream>>>(kbuf, vbuf, scal4, q_last, m_last);
  k3_kern<<<88, 256, 0, stream>>>(x, f_last, m_last, W_f, b_f, W1, b1, g1,
                                  be1, W2, b2, d_out);
}